// Round 3
// baseline (698.888 us; speedup 1.0000x reference)
//
#include <hip/hip_runtime.h>
#include <hip/hip_bf16.h>

// ---------------- problem constants ----------------
#define PIX    196          // 14*14
#define EPSN   1e-5f

// workspace (float units): [0..2] = max|w1|,|w2|,|w3| ; H1 ; H2   (~12.9 MB)
#define OFF_H1 16
#define N_H    (32*256*196)
#define OFF_H2 (OFF_H1 + N_H)

__device__ __forceinline__ void qparams(int e, float& ascale, float& nq) {
    ascale = e == 0 ? 3.f : (e == 1 ? 15.f : 255.f);   // lv-1 for lv=4,16,256
    nq     = e == 0 ? 1.f : (e == 1 ? 7.f : 127.f);    // lv/2-1
}

// ---------------- max|w| : one block per tensor, plain store ----------------
__global__ __launch_bounds__(1024) void maxabs_kernel(
        const float* __restrict__ w1, const float* __restrict__ w2,
        const float* __restrict__ w3, float* __restrict__ wmax) {
    int t = blockIdx.x;
    const float* w = t == 0 ? w1 : (t == 1 ? w2 : w3);
    int n = (t == 1) ? 256 * 256 * 9 : 256 * 1024;
    float m = 0.f;
    for (int i = threadIdx.x; i < n; i += 1024) m = fmaxf(m, fabsf(w[i]));
    __shared__ float red[1024];
    red[threadIdx.x] = m;
    __syncthreads();
    for (int s = 512; s > 0; s >>= 1) {
        if (threadIdx.x < s) red[threadIdx.x] = fmaxf(red[threadIdx.x], red[threadIdx.x + s]);
        __syncthreads();
    }
    if (threadIdx.x == 0) wmax[t] = red[0];
}

// ---------------- conv1: 1x1, 1024 -> 256, + BN1 + ReLU ----------------
// grid (8, 32): x = 32-co tile, y = sample. threads: cg = tid&15 (co pair), y = tid>>4 (row).
// LDS: 50176 + 8704 = 58880 B
__global__ __launch_bounds__(256) void conv1_kernel(
        const float* __restrict__ x, const int* __restrict__ mask,
        const float* __restrict__ w1, float* __restrict__ ws,
        const float* __restrict__ bg, const float* __restrict__ bb,
        const float* __restrict__ bm, const float* __restrict__ bv) {
    int b = blockIdx.y, co0 = blockIdx.x * 32;
    int e = mask[b];
    float ascale, nq;
    qparams(e, ascale, nq);
    float ainv = 1.f / ascale;
    float s = ws[0] + 1e-12f;
    float qi = nq / s, qs = s / nq;
    const float* xb = x + b * 1024 * PIX;
    float* h1 = ws + OFF_H1 + b * 256 * PIX;

    __shared__ float xs[64][196];
    __shared__ float wsm[64][34];

    int tid = threadIdx.x, cg = tid & 15, y = tid >> 4;
    float acc[2][14] = {};

    for (int k0 = 0; k0 < 1024; k0 += 64) {
        #pragma unroll 4
        for (int j = 0; j < 49; ++j) {              // 64*196 = 49*256
            int idx = j * 256 + tid;
            int ci = idx / 196, p = idx - ci * 196;
            float v = xb[(k0 + ci) * PIX + p];
            v = fminf(fmaxf(v, 0.f), 1.f);
            xs[ci][p] = rintf(v * ascale) * ainv;   // qact
        }
        #pragma unroll
        for (int j = 0; j < 8; ++j) {               // 64*32 = 8*256
            int idx = j * 256 + tid;
            int co = idx >> 6, kk = idx & 63;       // kk fastest -> coalesced global read
            float v = w1[(co0 + co) * 1024 + k0 + kk];
            wsm[kk][co] = rintf(v * qi) * qs;       // qw on the fly
        }
        __syncthreads();
        if (y < 14) {
            for (int kk = 0; kk < 64; ++kk) {
                float2 wv = *(const float2*)&wsm[kk][cg * 2];
                const float* row = &xs[kk][y * 14];
                #pragma unroll
                for (int c = 0; c < 7; ++c) {
                    float2 xv = *(const float2*)&row[c * 2];
                    acc[0][2 * c]     += wv.x * xv.x;
                    acc[0][2 * c + 1] += wv.x * xv.y;
                    acc[1][2 * c]     += wv.y * xv.x;
                    acc[1][2 * c + 1] += wv.y * xv.y;
                }
            }
        }
        __syncthreads();
    }
    if (y < 14) {
        #pragma unroll
        for (int cl = 0; cl < 2; ++cl) {
            int co = co0 + cg * 2 + cl;
            float inv = bg[co] * rsqrtf(bv[co] + EPSN);
            float beta = bb[co] - bm[co] * inv;
            #pragma unroll
            for (int p = 0; p < 14; ++p)
                h1[co * PIX + y * 14 + p] = fmaxf(acc[cl][p] * inv + beta, 0.f);
        }
    }
}

// ---------------- conv2: 3x3 pad1, 256 -> 256, + BN2 + ReLU ----------------
// grid (8, 32). ci-tile 16. LDS: 14336 + 19584 = 33920 B
__global__ __launch_bounds__(256) void conv2_kernel(
        const int* __restrict__ mask, const float* __restrict__ w2,
        float* __restrict__ ws,
        const float* __restrict__ bg, const float* __restrict__ bb,
        const float* __restrict__ bm, const float* __restrict__ bv) {
    int b = blockIdx.y, co0 = blockIdx.x * 32;
    int e = mask[b];
    float ascale, nq;
    qparams(e, ascale, nq);
    float ainv = 1.f / ascale;
    float s = ws[1] + 1e-12f;
    float qi = nq / s, qs = s / nq;
    const float* h1 = ws + OFF_H1 + b * 256 * PIX;
    float* h2 = ws + OFF_H2 + b * 256 * PIX;

    __shared__ float xs[16][14][16];    // zero halo at col 0 and 15
    __shared__ float wall[9][16][34];

    int tid = threadIdx.x, cg = tid & 15, y = tid >> 4;

    for (int i = tid; i < 16 * 14; i += 256) {      // zero halo once
        int ci = i / 14, yy = i - ci * 14;
        xs[ci][yy][0] = 0.f;
        xs[ci][yy][15] = 0.f;
    }

    float acc[2][14] = {};

    for (int ci0 = 0; ci0 < 256; ci0 += 16) {
        __syncthreads();                            // protect previous readers (and halo)
        #pragma unroll 4
        for (int j = 0; j < 13; ++j) {              // 16*196 = 3136 elements
            int idx = j * 256 + tid;
            if (idx < 3136) {
                int ci = idx / 196, p = idx - ci * 196;
                int yy = p / 14, xx = p - yy * 14;
                float v = h1[(ci0 + ci) * PIX + p];
                v = fminf(fmaxf(v, 0.f), 1.f);
                xs[ci][yy][xx + 1] = rintf(v * ascale) * ainv;
            }
        }
        #pragma unroll 3
        for (int j = 0; j < 18; ++j) {              // 9*16*32 = 4608 = 18*256
            int idx = j * 256 + tid;
            int co = idx / 144;
            int r = idx - co * 144;
            int kk = r / 9, tap = r - kk * 9;
            float v = w2[(co0 + co) * 2304 + (ci0 + kk) * 9 + tap];
            wall[tap][kk][co] = rintf(v * qi) * qs;
        }
        __syncthreads();
        if (y < 14) {
            #pragma unroll
            for (int tap = 0; tap < 9; ++tap) {
                const int ky = tap / 3, kx = tap - ky * 3;
                int yy = y + ky - 1;
                if (yy >= 0 && yy < 14) {
                    for (int kk = 0; kk < 16; ++kk) {
                        float2 wv = *(const float2*)&wall[tap][kk][cg * 2];
                        const float4* rp = (const float4*)&xs[kk][yy][0];
                        float4 r0 = rp[0], r1 = rp[1], r2 = rp[2], r3 = rp[3];
                        float xv[16] = {r0.x, r0.y, r0.z, r0.w, r1.x, r1.y, r1.z, r1.w,
                                        r2.x, r2.y, r2.z, r2.w, r3.x, r3.y, r3.z, r3.w};
                        #pragma unroll
                        for (int p = 0; p < 14; ++p) {
                            float xval = xv[p + kx];
                            acc[0][p] += wv.x * xval;
                            acc[1][p] += wv.y * xval;
                        }
                    }
                }
            }
        }
    }
    if (y < 14) {
        #pragma unroll
        for (int cl = 0; cl < 2; ++cl) {
            int co = co0 + cg * 2 + cl;
            float inv = bg[co] * rsqrtf(bv[co] + EPSN);
            float beta = bb[co] - bm[co] * inv;
            #pragma unroll
            for (int p = 0; p < 14; ++p)
                h2[co * PIX + y * 14 + p] = fmaxf(acc[cl][p] * inv + beta, 0.f);
        }
    }
}

// ---------------- conv3: 1x1, 256 -> 1024, f32 store into d_out ----------------
// grid (32, 32): 32-co tiles. LDS: 58880 B
__global__ __launch_bounds__(256) void conv3_kernel(
        const int* __restrict__ mask, const float* __restrict__ w3,
        const float* __restrict__ ws, float* __restrict__ out) {
    int b = blockIdx.y, co0 = blockIdx.x * 32;
    int e = mask[b];
    float ascale, nq;
    qparams(e, ascale, nq);
    float ainv = 1.f / ascale;
    float s = ws[2] + 1e-12f;
    float qi = nq / s, qs = s / nq;
    const float* h2 = ws + OFF_H2 + b * 256 * PIX;
    float* ob = out + b * 1024 * PIX;

    __shared__ float xs[64][196];
    __shared__ float wsm[64][34];

    int tid = threadIdx.x, cg = tid & 15, y = tid >> 4;
    float acc[2][14] = {};

    for (int k0 = 0; k0 < 256; k0 += 64) {
        #pragma unroll 4
        for (int j = 0; j < 49; ++j) {
            int idx = j * 256 + tid;
            int ci = idx / 196, p = idx - ci * 196;
            float v = h2[(k0 + ci) * PIX + p];
            v = fminf(fmaxf(v, 0.f), 1.f);
            xs[ci][p] = rintf(v * ascale) * ainv;
        }
        #pragma unroll
        for (int j = 0; j < 8; ++j) {
            int idx = j * 256 + tid;
            int co = idx >> 6, kk = idx & 63;
            float v = w3[(co0 + co) * 256 + k0 + kk];
            wsm[kk][co] = rintf(v * qi) * qs;
        }
        __syncthreads();
        if (y < 14) {
            for (int kk = 0; kk < 64; ++kk) {
                float2 wv = *(const float2*)&wsm[kk][cg * 2];
                const float* row = &xs[kk][y * 14];
                #pragma unroll
                for (int c = 0; c < 7; ++c) {
                    float2 xv = *(const float2*)&row[c * 2];
                    acc[0][2 * c]     += wv.x * xv.x;
                    acc[0][2 * c + 1] += wv.x * xv.y;
                    acc[1][2 * c]     += wv.y * xv.x;
                    acc[1][2 * c + 1] += wv.y * xv.y;
                }
            }
        }
        __syncthreads();
    }
    if (y < 14) {
        #pragma unroll
        for (int cl = 0; cl < 2; ++cl) {
            int co = co0 + cg * 2 + cl;
            #pragma unroll
            for (int p = 0; p < 14; ++p)
                ob[co * PIX + y * 14 + p] = acc[cl][p];
        }
    }
}

// ---------------- GroupNorm(4) + affine + residual + ReLU, in place on f32 d_out ----------------
// grid 128 = 32 samples * 4 groups; each group = 256 ch * 196 px = 50176 elems
__global__ __launch_bounds__(256) void gn_kernel(
        float* __restrict__ out, const float* __restrict__ x,
        const float* __restrict__ gg, const float* __restrict__ gb) {
    int b = blockIdx.x >> 2, g = blockIdx.x & 3;
    const int boff = (b * 1024 + g * 256) * PIX;
    float* base = out + boff;
    const float* xbase = x + boff;

    int tid = threadIdx.x;
    float sum = 0.f, ssum = 0.f;
    for (int i = tid; i < 50176; i += 256) {
        float v = base[i];
        sum += v;
        ssum += v * v;
    }
    __shared__ float rs[256], rss[256];
    rs[tid] = sum; rss[tid] = ssum;
    __syncthreads();
    for (int st = 128; st > 0; st >>= 1) {
        if (tid < st) { rs[tid] += rs[tid + st]; rss[tid] += rss[tid + st]; }
        __syncthreads();
    }
    float mu = rs[0] * (1.f / 50176.f);
    float var = rss[0] * (1.f / 50176.f) - mu * mu;
    float rstd = rsqrtf(var + EPSN);

    for (int i = tid; i < 50176; i += 256) {
        int c = i / 196;
        int gc = g * 256 + c;
        float v = (base[i] - mu) * rstd * gg[gc] + gb[gc];
        v += xbase[i];
        base[i] = fmaxf(v, 0.f);
    }
}

// ---------------- launch ----------------
extern "C" void kernel_launch(void* const* d_in, const int* in_sizes, int n_in,
                              void* d_out, int out_size, void* d_ws, size_t ws_size,
                              hipStream_t stream) {
    (void)in_sizes; (void)n_in; (void)out_size; (void)ws_size;
    const float* x    = (const float*)d_in[0];
    const int*   mask = (const int*)d_in[1];
    const float* w1   = (const float*)d_in[2];
    const float* w2   = (const float*)d_in[3];
    const float* w3   = (const float*)d_in[4];
    const float* b1g  = (const float*)d_in[5];
    const float* b1b  = (const float*)d_in[6];
    const float* b1m  = (const float*)d_in[7];
    const float* b1v  = (const float*)d_in[8];
    const float* b2g  = (const float*)d_in[9];
    const float* b2b  = (const float*)d_in[10];
    const float* b2m  = (const float*)d_in[11];
    const float* b2v  = (const float*)d_in[12];
    const float* gng  = (const float*)d_in[13];
    const float* gnb  = (const float*)d_in[14];
    float* ws = (float*)d_ws;
    float* out = (float*)d_out;

    maxabs_kernel<<<3, 1024, 0, stream>>>(w1, w2, w3, ws);
    conv1_kernel<<<dim3(8, 32), 256, 0, stream>>>(x, mask, w1, ws, b1g, b1b, b1m, b1v);
    conv2_kernel<<<dim3(8, 32), 256, 0, stream>>>(mask, w2, ws, b2g, b2b, b2m, b2v);
    conv3_kernel<<<dim3(32, 32), 256, 0, stream>>>(mask, w3, ws, out);
    gn_kernel<<<128, 256, 0, stream>>>(out, x, gng, gnb);
}

// Round 4
// 341.149 us; speedup vs baseline: 2.0486x; 2.0486x over previous
//
#include <hip/hip_runtime.h>
#include <hip/hip_bf16.h>

typedef __attribute__((ext_vector_type(8))) short short8;
typedef __attribute__((ext_vector_type(4))) float f32x4;

#define PIX  196
#define EPSN 1e-5f

// ---------------- workspace byte layout (~20.8 MB) ----------------
#define BO_WMAX 0
#define BO_XQ   256                      // [32][196][1024] bf16 = 12,845,056 B
#define BO_W2Q  BO_XQ                    // reuse after conv1: [3][9][256][256] = 3,538,944 B
#define BO_W3Q  (BO_XQ + 3538944)        // [3][1024][256] = 1,572,864 B
#define BO_H1Q  (BO_XQ + 12845056)       // [32][196][256] bf16 = 3,211,264 B
#define BO_H2Q  (BO_H1Q + 3211264)
#define BO_W1Q  (BO_H2Q + 3211264)       // [3][256][1024] = 1,572,864 B

__device__ __forceinline__ float e_ascale(int e) { return e == 0 ? 3.f : (e == 1 ? 15.f : 255.f); }
__device__ __forceinline__ float e_nq(int e)     { return e == 0 ? 1.f : (e == 1 ? 7.f : 127.f); }

// ---------------- zero wmax ----------------
__global__ void zero_kernel(unsigned* wmax) {
    if (threadIdx.x < 4) wmax[threadIdx.x] = 0u;
}

// ---------------- max|w| (atomicMax on positive-float bits) ----------------
__global__ __launch_bounds__(256) void maxabs_kernel(
        const float* __restrict__ w1, const float* __restrict__ w2,
        const float* __restrict__ w3, unsigned* __restrict__ wmax) {
    int t = blockIdx.y;
    const float* w = t == 0 ? w1 : (t == 1 ? w2 : w3);
    int n = (t == 1) ? 256 * 256 * 9 : 256 * 1024;
    float m = 0.f;
    for (int i = blockIdx.x * 256 + threadIdx.x; i < n; i += gridDim.x * 256)
        m = fmaxf(m, fabsf(w[i]));
    __shared__ float red[256];
    red[threadIdx.x] = m;
    __syncthreads();
    for (int s = 128; s > 0; s >>= 1) {
        if (threadIdx.x < s) red[threadIdx.x] = fmaxf(red[threadIdx.x], red[threadIdx.x + s]);
        __syncthreads();
    }
    if (threadIdx.x == 0) atomicMax(&wmax[t], __float_as_uint(red[0]));
}

// ---------------- weight -> integer bf16, 3 experts, transposed layouts ----------------
// which: 0 = w1 (256x1024 -> [e][co][ci]), 1 = w2 (256x256x3x3 -> [e][tap][co][ci]), 2 = w3 (1024x256 -> [e][co][ci])
__global__ __launch_bounds__(256) void prepw_kernel(
        const float* __restrict__ w, char* wsb, int which) {
    int n = (which == 1) ? 589824 : 262144;
    int idx = blockIdx.x * 256 + threadIdx.x;
    if (idx >= n) return;
    const unsigned* wmaxu = (const unsigned*)(wsb + BO_WMAX);
    float s = __uint_as_float(wmaxu[which]) + 1e-12f;
    float v = w[idx];
    __hip_bfloat16* dst;
    size_t off, estride;
    if (which == 0)      { dst = (__hip_bfloat16*)(wsb + BO_W1Q); off = idx; estride = 262144; }
    else if (which == 1) {
        int co = idx / 2304, r = idx - co * 2304, ci = r / 9, tap = r - ci * 9;
        dst = (__hip_bfloat16*)(wsb + BO_W2Q);
        off = ((size_t)tap * 256 + co) * 256 + ci; estride = 589824;
    } else               { dst = (__hip_bfloat16*)(wsb + BO_W3Q); off = idx; estride = 262144; }
    #pragma unroll
    for (int e = 0; e < 3; ++e) {
        float q = rintf(v / s * e_nq(e));            // integer in [-127,127]: exact in bf16
        dst[e * estride + off] = __float2bfloat16(q);
    }
}

// ---------------- x -> qact integer bf16, NCHW -> NHWC transpose via LDS ----------------
// grid (16 ci-chunks, 32 samples), 256 thr. LDS 64x197 f32.
__global__ __launch_bounds__(256) void prepx_kernel(
        const float* __restrict__ x, const int* __restrict__ mask, char* wsb) {
    int b = blockIdx.y, c0 = blockIdx.x * 64;
    float ascale = e_ascale(mask[b]);
    __shared__ float xs[64][197];
    int tid = threadIdx.x;
    for (int idx = tid; idx < 64 * 196; idx += 256) {
        int ci = idx / 196, p = idx - ci * 196;
        xs[ci][p] = x[((size_t)b * 1024 + c0 + ci) * 196 + p];
    }
    __syncthreads();
    __hip_bfloat16* xq = (__hip_bfloat16*)(wsb + BO_XQ);
    for (int idx = tid; idx < 196 * 64; idx += 256) {
        int p = idx / 64, ci = idx - p * 64;
        float v = fminf(fmaxf(xs[ci][p], 0.f), 1.f);
        xq[((size_t)b * 196 + p) * 1024 + c0 + ci] = __float2bfloat16(rintf(v * ascale));
    }
}

// ---------------- conv1: 1x1 1024->256 MFMA + BN1 + ReLU + qact ----------------
// grid (13 px-tiles, 2 co-groups(128), 32 samples); wave = 2 co-tiles
__global__ __launch_bounds__(256) void conv1_mfma(
        char* wsb, const int* __restrict__ mask,
        const float* __restrict__ bg, const float* __restrict__ bb,
        const float* __restrict__ bm, const float* __restrict__ bv) {
    int b = blockIdx.z;
    int e = mask[b];
    float ascale = e_ascale(e), nq = e_nq(e);
    const unsigned* wmaxu = (const unsigned*)(wsb + BO_WMAX);
    float s1 = __uint_as_float(wmaxu[0]) + 1e-12f;
    float kscale = (s1 / nq) / ascale;

    const short* xq  = (const short*)(wsb + BO_XQ);
    const short* w1q = (const short*)(wsb + BO_W1Q);
    __hip_bfloat16* h1q = (__hip_bfloat16*)(wsb + BO_H1Q);

    int tid = threadIdx.x, w = tid >> 6, lane = tid & 63;
    int r15 = lane & 15, g = lane >> 4;
    int px0 = blockIdx.x * 16;
    int coA = blockIdx.y * 128 + w * 16;
    int apx = min(px0 + r15, 195);

    const short* ap  = xq + ((size_t)(b * 196 + apx)) * 1024 + g * 8;
    const short* bpA = w1q + ((size_t)(e * 256 + coA + r15)) * 1024 + g * 8;
    const short* bpB = bpA + (size_t)64 * 1024;

    f32x4 accA = {0.f, 0.f, 0.f, 0.f}, accB = {0.f, 0.f, 0.f, 0.f};
    #pragma unroll 8
    for (int kk = 0; kk < 32; ++kk) {
        short8 a  = *(const short8*)(ap + kk * 32);
        short8 b1 = *(const short8*)(bpA + kk * 32);
        short8 b2 = *(const short8*)(bpB + kk * 32);
        accA = __builtin_amdgcn_mfma_f32_16x16x32_bf16(a, b1, accA, 0, 0, 0);
        accB = __builtin_amdgcn_mfma_f32_16x16x32_bf16(a, b2, accB, 0, 0, 0);
    }
    #pragma unroll
    for (int t = 0; t < 2; ++t) {
        f32x4 acc = t ? accB : accA;
        int co = coA + t * 64 + r15;
        float inv = bg[co] * rsqrtf(bv[co] + EPSN);
        float m = kscale * inv;
        float beta = bb[co] - bm[co] * inv;
        #pragma unroll
        for (int r = 0; r < 4; ++r) {
            int px = px0 + g * 4 + r;
            if (px < 196) {
                float h = fmaxf(acc[r] * m + beta, 0.f);
                float hq = rintf(fminf(h, 1.f) * ascale);
                h1q[((size_t)(b * 196 + px)) * 256 + co] = __float2bfloat16(hq);
            }
        }
    }
}

// ---------------- conv2: 3x3 256->256 implicit-GEMM MFMA + BN2 + ReLU + qact ----------------
// grid (13, 4 co-groups(64), 32)
__global__ __launch_bounds__(256) void conv2_mfma(
        char* wsb, const int* __restrict__ mask,
        const float* __restrict__ bg, const float* __restrict__ bb,
        const float* __restrict__ bm, const float* __restrict__ bv) {
    int b = blockIdx.z;
    int e = mask[b];
    float ascale = e_ascale(e), nq = e_nq(e);
    const unsigned* wmaxu = (const unsigned*)(wsb + BO_WMAX);
    float s2 = __uint_as_float(wmaxu[1]) + 1e-12f;
    float kscale = (s2 / nq) / ascale;

    const short* h1q = (const short*)(wsb + BO_H1Q);
    const short* w2q = (const short*)(wsb + BO_W2Q);
    __hip_bfloat16* h2q = (__hip_bfloat16*)(wsb + BO_H2Q);

    int tid = threadIdx.x, w = tid >> 6, lane = tid & 63;
    int r15 = lane & 15, g = lane >> 4;
    int px0 = blockIdx.x * 16;
    int co0 = blockIdx.y * 64 + w * 16;
    int apx = min(px0 + r15, 195);
    int yy = apx / 14, xx = apx - yy * 14;

    const short* abase = h1q + ((size_t)(b * 196 + apx)) * 256 + g * 8;
    f32x4 acc = {0.f, 0.f, 0.f, 0.f};

    #pragma unroll
    for (int tap = 0; tap < 9; ++tap) {
        int dy = tap / 3 - 1, dx = tap % 3 - 1;
        bool valid = ((unsigned)(yy + dy) < 14u) && ((unsigned)(xx + dx) < 14u);
        const short* ap = abase + (dy * 14 + dx) * 256;
        const short* bp = w2q + (((size_t)(e * 9 + tap) * 256) + co0 + r15) * 256 + g * 8;
        #pragma unroll
        for (int kk = 0; kk < 8; ++kk) {
            short8 a = {0, 0, 0, 0, 0, 0, 0, 0};
            if (valid) a = *(const short8*)(ap + kk * 32);
            short8 bw = *(const short8*)(bp + kk * 32);
            acc = __builtin_amdgcn_mfma_f32_16x16x32_bf16(a, bw, acc, 0, 0, 0);
        }
    }
    int co = co0 + r15;
    float inv = bg[co] * rsqrtf(bv[co] + EPSN);
    float m = kscale * inv;
    float beta = bb[co] - bm[co] * inv;
    #pragma unroll
    for (int r = 0; r < 4; ++r) {
        int px = px0 + g * 4 + r;
        if (px < 196) {
            float h = fmaxf(acc[r] * m + beta, 0.f);
            float hq = rintf(fminf(h, 1.f) * ascale);
            h2q[((size_t)(b * 196 + px)) * 256 + co] = __float2bfloat16(hq);
        }
    }
}

// ---------------- conv3: 1x1 256->1024 MFMA, f32 NCHW store to d_out ----------------
// grid (13, 16 co-groups(64), 32)
__global__ __launch_bounds__(256) void conv3_mfma(
        char* wsb, const int* __restrict__ mask, float* __restrict__ out) {
    int b = blockIdx.z;
    int e = mask[b];
    float ascale = e_ascale(e), nq = e_nq(e);
    const unsigned* wmaxu = (const unsigned*)(wsb + BO_WMAX);
    float s3 = __uint_as_float(wmaxu[2]) + 1e-12f;
    float kscale = (s3 / nq) / ascale;

    const short* h2q = (const short*)(wsb + BO_H2Q);
    const short* w3q = (const short*)(wsb + BO_W3Q);

    int tid = threadIdx.x, w = tid >> 6, lane = tid & 63;
    int r15 = lane & 15, g = lane >> 4;
    int px0 = blockIdx.x * 16;
    int co0 = blockIdx.y * 64 + w * 16;
    int apx = min(px0 + r15, 195);

    const short* ap = h2q + ((size_t)(b * 196 + apx)) * 256 + g * 8;
    const short* bp = w3q + ((size_t)(e * 1024 + co0 + r15)) * 256 + g * 8;

    f32x4 acc = {0.f, 0.f, 0.f, 0.f};
    #pragma unroll
    for (int kk = 0; kk < 8; ++kk) {
        short8 a = *(const short8*)(ap + kk * 32);
        short8 bw = *(const short8*)(bp + kk * 32);
        acc = __builtin_amdgcn_mfma_f32_16x16x32_bf16(a, bw, acc, 0, 0, 0);
    }
    int co = co0 + r15;
    #pragma unroll
    for (int r = 0; r < 4; ++r) {
        int px = px0 + g * 4 + r;
        if (px < 196)
            out[((size_t)b * 1024 + co) * 196 + px] = acc[r] * kscale;
    }
}

// ---------------- GroupNorm(4) + affine + residual + ReLU, in place on f32 d_out ----------------
__global__ __launch_bounds__(256) void gn_kernel(
        float* __restrict__ out, const float* __restrict__ x,
        const float* __restrict__ gg, const float* __restrict__ gb) {
    int b = blockIdx.x >> 2, g = blockIdx.x & 3;
    const size_t boff = ((size_t)b * 1024 + g * 256) * PIX;
    float* base = out + boff;
    const float* xbase = x + boff;

    int tid = threadIdx.x;
    float sum = 0.f, ssum = 0.f;
    for (int i = tid; i < 50176; i += 256) {
        float v = base[i];
        sum += v; ssum += v * v;
    }
    __shared__ float rs[256], rss[256];
    rs[tid] = sum; rss[tid] = ssum;
    __syncthreads();
    for (int st = 128; st > 0; st >>= 1) {
        if (tid < st) { rs[tid] += rs[tid + st]; rss[tid] += rss[tid + st]; }
        __syncthreads();
    }
    float mu = rs[0] * (1.f / 50176.f);
    float var = rss[0] * (1.f / 50176.f) - mu * mu;
    float rstd = rsqrtf(var + EPSN);

    for (int i = tid; i < 50176; i += 256) {
        int c = i / 196;
        int gc = g * 256 + c;
        float v = (base[i] - mu) * rstd * gg[gc] + gb[gc];
        v += xbase[i];
        base[i] = fmaxf(v, 0.f);
    }
}

// ---------------- launch ----------------
extern "C" void kernel_launch(void* const* d_in, const int* in_sizes, int n_in,
                              void* d_out, int out_size, void* d_ws, size_t ws_size,
                              hipStream_t stream) {
    (void)in_sizes; (void)n_in; (void)out_size; (void)ws_size;
    const float* x    = (const float*)d_in[0];
    const int*   mask = (const int*)d_in[1];
    const float* w1   = (const float*)d_in[2];
    const float* w2   = (const float*)d_in[3];
    const float* w3   = (const float*)d_in[4];
    const float* b1g  = (const float*)d_in[5];
    const float* b1b  = (const float*)d_in[6];
    const float* b1m  = (const float*)d_in[7];
    const float* b1v  = (const float*)d_in[8];
    const float* b2g  = (const float*)d_in[9];
    const float* b2b  = (const float*)d_in[10];
    const float* b2m  = (const float*)d_in[11];
    const float* b2v  = (const float*)d_in[12];
    const float* gng  = (const float*)d_in[13];
    const float* gnb  = (const float*)d_in[14];
    char* wsb = (char*)d_ws;
    float* out = (float*)d_out;
    unsigned* wmax = (unsigned*)(wsb + BO_WMAX);

    zero_kernel<<<1, 64, 0, stream>>>(wmax);
    maxabs_kernel<<<dim3(48, 3), 256, 0, stream>>>(w1, w2, w3, wmax);
    prepw_kernel<<<1024, 256, 0, stream>>>(w1, wsb, 0);
    prepx_kernel<<<dim3(16, 32), 256, 0, stream>>>(x, mask, wsb);
    conv1_mfma<<<dim3(13, 2, 32), 256, 0, stream>>>(wsb, mask, b1g, b1b, b1m, b1v);
    prepw_kernel<<<2304, 256, 0, stream>>>(w2, wsb, 1);   // w2q/w3q overwrite dead xq region
    prepw_kernel<<<1024, 256, 0, stream>>>(w3, wsb, 2);
    conv2_mfma<<<dim3(13, 4, 32), 256, 0, stream>>>(wsb, mask, b2g, b2b, b2m, b2v);
    conv3_mfma<<<dim3(13, 16, 32), 256, 0, stream>>>(wsb, mask, out);
    gn_kernel<<<128, 256, 0, stream>>>(out, x, gng, gnb);
}

// Round 5
// 166.434 us; speedup vs baseline: 4.1992x; 2.0498x over previous
//
#include <hip/hip_runtime.h>
#include <hip/hip_bf16.h>

typedef __attribute__((ext_vector_type(8))) short short8;
typedef __attribute__((ext_vector_type(4))) float f32x4;

#define PIX  196
#define EPSN 1e-5f

// ---------------- workspace byte layout (~20.8 MB) ----------------
#define BO_WMAX 0
#define BO_XQ   256                      // [32][196][1024] bf16 = 12,845,056 B
#define BO_W2Q  BO_XQ                    // reuse after conv1: [3][9][256][256] bf16
#define BO_W3Q  (BO_XQ + 3538944)        // [3][1024][256] bf16
#define BO_H1Q  (BO_XQ + 12845056)       // [32][196][256] bf16
#define BO_H2Q  (BO_H1Q + 3211264)
#define BO_W1Q  (BO_H2Q + 3211264)       // [3][256][1024] bf16

__device__ __forceinline__ float e_ascale(int e) { return e == 0 ? 3.f : (e == 1 ? 15.f : 255.f); }
__device__ __forceinline__ float e_nq(int e)     { return e == 0 ? 1.f : (e == 1 ? 7.f : 127.f); }

__device__ __forceinline__ f32x4 mfma16(short8 a, short8 b, f32x4 c) {
    return __builtin_amdgcn_mfma_f32_16x16x32_bf16(a, b, c, 0, 0, 0);
}

// ---------------- zero wmax ----------------
__global__ void zero_kernel(unsigned* wmax) {
    if (threadIdx.x < 4) wmax[threadIdx.x] = 0u;
}

// ---------------- max|w| ----------------
__global__ __launch_bounds__(256) void maxabs_kernel(
        const float* __restrict__ w1, const float* __restrict__ w2,
        const float* __restrict__ w3, unsigned* __restrict__ wmax) {
    int t = blockIdx.y;
    const float* w = t == 0 ? w1 : (t == 1 ? w2 : w3);
    int n = (t == 1) ? 256 * 256 * 9 : 256 * 1024;
    float m = 0.f;
    for (int i = blockIdx.x * 256 + threadIdx.x; i < n; i += gridDim.x * 256)
        m = fmaxf(m, fabsf(w[i]));
    __shared__ float red[256];
    red[threadIdx.x] = m;
    __syncthreads();
    for (int s = 128; s > 0; s >>= 1) {
        if (threadIdx.x < s) red[threadIdx.x] = fmaxf(red[threadIdx.x], red[threadIdx.x + s]);
        __syncthreads();
    }
    if (threadIdx.x == 0) atomicMax(&wmax[t], __float_as_uint(red[0]));
}

// ---------------- weight -> integer bf16, 3 experts ----------------
__global__ __launch_bounds__(256) void prepw_kernel(
        const float* __restrict__ w, char* wsb, int which) {
    int n = (which == 1) ? 589824 : 262144;
    int idx = blockIdx.x * 256 + threadIdx.x;
    if (idx >= n) return;
    const unsigned* wmaxu = (const unsigned*)(wsb + BO_WMAX);
    float s = __uint_as_float(wmaxu[which]) + 1e-12f;
    float v = w[idx];
    __hip_bfloat16* dst;
    size_t off, estride;
    if (which == 0)      { dst = (__hip_bfloat16*)(wsb + BO_W1Q); off = idx; estride = 262144; }
    else if (which == 1) {
        int co = idx / 2304, r = idx - co * 2304, ci = r / 9, tap = r - ci * 9;
        dst = (__hip_bfloat16*)(wsb + BO_W2Q);
        off = ((size_t)tap * 256 + co) * 256 + ci; estride = 589824;
    } else               { dst = (__hip_bfloat16*)(wsb + BO_W3Q); off = idx; estride = 262144; }
    #pragma unroll
    for (int e = 0; e < 3; ++e) {
        float q = rintf(v / s * e_nq(e));            // integer in [-127,127]: exact in bf16
        dst[e * estride + off] = __float2bfloat16(q);
    }
}

// ---------------- x -> qact integer bf16, NCHW -> NHWC ----------------
__global__ __launch_bounds__(256) void prepx_kernel(
        const float* __restrict__ x, const int* __restrict__ mask, char* wsb) {
    int b = blockIdx.y, c0 = blockIdx.x * 64;
    float ascale = e_ascale(mask[b]);
    __shared__ float xs[64][197];
    int tid = threadIdx.x;
    for (int idx = tid; idx < 64 * 196; idx += 256) {
        int ci = idx / 196, p = idx - ci * 196;
        xs[ci][p] = x[((size_t)b * 1024 + c0 + ci) * 196 + p];
    }
    __syncthreads();
    __hip_bfloat16* xq = (__hip_bfloat16*)(wsb + BO_XQ);
    for (int idx = tid; idx < 196 * 64; idx += 256) {
        int p = idx / 64, ci = idx - p * 64;
        float v = fminf(fmaxf(xs[ci][p], 0.f), 1.f);
        xq[((size_t)b * 196 + p) * 1024 + c0 + ci] = __float2bfloat16(rintf(v * ascale));
    }
}

// ================= conv1: 1x1 1024->256, LDS-staged MFMA GEMM =================
// grid (2 M-half, 2 N-half(128co), 32); 4 waves: wave = 7 M-frags x 2 N-frags (32co)
__global__ __launch_bounds__(256) void conv1_mfma(
        char* wsb, const int* __restrict__ mask,
        const float* __restrict__ bg, const float* __restrict__ bb,
        const float* __restrict__ bm, const float* __restrict__ bv) {
    int b = blockIdx.z;
    int e = mask[b];
    float ascale = e_ascale(e), nq = e_nq(e);
    float s1 = __uint_as_float(((const unsigned*)(wsb + BO_WMAX))[0]) + 1e-12f;
    float kscale = (s1 / nq) / ascale;

    const short* xq  = (const short*)(wsb + BO_XQ) + (size_t)b * 196 * 1024;
    const short* w1q = (const short*)(wsb + BO_W1Q) + (size_t)e * 256 * 1024;
    __hip_bfloat16* h1q = (__hip_bfloat16*)(wsb + BO_H1Q) + (size_t)b * 196 * 256;

    __shared__ short As[112 * 72];   // [px][64ci], row stride 72 -> 2-way banks
    __shared__ short Bs[128 * 72];   // [co][64ci]

    int tid = threadIdx.x, w = tid >> 6, lane = tid & 63, r15 = lane & 15, g = lane >> 4;
    int px0 = blockIdx.x * 112;
    int coB = blockIdx.y * 128;
    int cow = coB + w * 32;

    f32x4 acc[7][2] = {};
    const short8 z8 = {0, 0, 0, 0, 0, 0, 0, 0};

    for (int k0 = 0; k0 < 1024; k0 += 64) {
        __syncthreads();
        #pragma unroll
        for (int it = 0; it < 4; ++it) {            // A: 112*8 = 896 chunks
            int idx = it * 256 + tid;
            if (idx < 896) {
                int px = idx >> 3, c = idx & 7;
                short8 v = z8;
                if (px0 + px < 196) v = *(const short8*)(xq + (size_t)(px0 + px) * 1024 + k0 + c * 8);
                *(short8*)(As + px * 72 + c * 8) = v;
            }
        }
        #pragma unroll
        for (int it = 0; it < 4; ++it) {            // B: 128*8 = 1024 chunks
            int idx = it * 256 + tid;
            int co = idx >> 3, c = idx & 7;
            *(short8*)(Bs + co * 72 + c * 8) =
                *(const short8*)(w1q + (size_t)(coB + co) * 1024 + k0 + c * 8);
        }
        __syncthreads();
        #pragma unroll
        for (int ks = 0; ks < 2; ++ks) {
            short8 bf0 = *(const short8*)(Bs + (w * 32 + r15) * 72 + ks * 32 + g * 8);
            short8 bf1 = *(const short8*)(Bs + (w * 32 + 16 + r15) * 72 + ks * 32 + g * 8);
            #pragma unroll
            for (int m = 0; m < 7; ++m) {
                short8 af = *(const short8*)(As + (m * 16 + r15) * 72 + ks * 32 + g * 8);
                acc[m][0] = mfma16(af, bf0, acc[m][0]);
                acc[m][1] = mfma16(af, bf1, acc[m][1]);
            }
        }
    }
    #pragma unroll
    for (int n = 0; n < 2; ++n) {
        int co = cow + n * 16 + r15;
        float inv = bg[co] * rsqrtf(bv[co] + EPSN);
        float mm = kscale * inv;
        float beta = bb[co] - bm[co] * inv;
        #pragma unroll
        for (int m = 0; m < 7; ++m)
            #pragma unroll
            for (int r = 0; r < 4; ++r) {
                int px = px0 + m * 16 + g * 4 + r;
                if (px < 196) {
                    float h = fmaxf(acc[m][n][r] * mm + beta, 0.f);
                    h1q[(size_t)px * 256 + co] = __float2bfloat16(rintf(fminf(h, 1.f) * ascale));
                }
            }
    }
}

// ================= conv2: 3x3 256->256, padded-patch LDS MFMA =================
// grid (2 M-half, 4 N(64co), 32); 4 waves: wave = 7 M-frags x 1 N-frag (16co)
__global__ __launch_bounds__(256) void conv2_mfma(
        char* wsb, const int* __restrict__ mask,
        const float* __restrict__ bg, const float* __restrict__ bb,
        const float* __restrict__ bm, const float* __restrict__ bv) {
    int b = blockIdx.z;
    int e = mask[b];
    float ascale = e_ascale(e), nq = e_nq(e);
    float s2 = __uint_as_float(((const unsigned*)(wsb + BO_WMAX))[1]) + 1e-12f;
    float kscale = (s2 / nq) / ascale;

    const short* h1q = (const short*)(wsb + BO_H1Q) + (size_t)b * 196 * 256;
    const short* w2q = (const short*)(wsb + BO_W2Q) + (size_t)e * 589824;
    __hip_bfloat16* h2q = (__hip_bfloat16*)(wsb + BO_H2Q) + (size_t)b * 196 * 256;

    __shared__ short Xs[16 * 16 * 32];   // padded spatial patch [sy][sx][32ci] -> 16 KB
    __shared__ short Ws9[9 * 64 * 32];   // [tap][co][32ci] -> 36 KB

    int tid = threadIdx.x, w = tid >> 6, lane = tid & 63, r15 = lane & 15, g = lane >> 4;
    int px0 = blockIdx.x * 112;
    int coB = blockIdx.y * 64;
    const short8 z8 = {0, 0, 0, 0, 0, 0, 0, 0};

    // zero the halo border once (never overwritten)
    if (tid < 240) {
        int bp = tid >> 2, c = tid & 3;
        int sy, sx;
        if (bp < 16)      { sy = 0;       sx = bp; }
        else if (bp < 32) { sy = 15;      sx = bp - 16; }
        else if (bp < 46) { sy = bp - 31; sx = 0; }
        else              { sy = bp - 45; sx = 15; }
        *(short8*)(Xs + (sy * 16 + sx) * 32 + c * 8) = z8;
    }

    f32x4 acc[7] = {};

    for (int ci0 = 0; ci0 < 256; ci0 += 32) {
        __syncthreads();
        #pragma unroll
        for (int it = 0; it < 4; ++it) {             // interior: 196*4 = 784 chunks
            int idx = it * 256 + tid;
            if (idx < 784) {
                int px = idx >> 2, c = idx & 3;
                int y = px / 14, xx = px - y * 14;
                *(short8*)(Xs + ((y + 1) * 16 + (xx + 1)) * 32 + c * 8) =
                    *(const short8*)(h1q + (size_t)px * 256 + ci0 + c * 8);
            }
        }
        #pragma unroll
        for (int it = 0; it < 9; ++it) {             // weights: 9*64*4 = 2304 chunks
            int idx = it * 256 + tid;
            int tap = idx >> 8, rem = idx & 255, co = rem >> 2, c = rem & 3;
            *(short8*)(Ws9 + (tap * 64 + co) * 32 + c * 8) =
                *(const short8*)(w2q + ((size_t)tap * 256 + coB + co) * 256 + ci0 + c * 8);
        }
        __syncthreads();

        short8 bf[9];
        #pragma unroll
        for (int tap = 0; tap < 9; ++tap)
            bf[tap] = *(const short8*)(Ws9 + (tap * 64 + w * 16 + r15) * 32 + g * 8);

        #pragma unroll
        for (int m = 0; m < 7; ++m) {
            int px = px0 + m * 16 + r15;
            int ap = min(px, 195);
            int y = ap / 14, xx = ap - y * 14;
            #pragma unroll
            for (int tap = 0; tap < 9; ++tap) {
                int ty = tap / 3, tx = tap - ty * 3;
                short8 af = *(const short8*)(Xs + ((y + ty) * 16 + (xx + tx)) * 32 + g * 8);
                acc[m] = mfma16(af, bf[tap], acc[m]);
            }
        }
    }
    int co = coB + w * 16 + r15;
    float inv = bg[co] * rsqrtf(bv[co] + EPSN);
    float mm = kscale * inv;
    float beta = bb[co] - bm[co] * inv;
    #pragma unroll
    for (int m = 0; m < 7; ++m)
        #pragma unroll
        for (int r = 0; r < 4; ++r) {
            int px = px0 + m * 16 + g * 4 + r;
            if (px < 196) {
                float h = fmaxf(acc[m][r] * mm + beta, 0.f);
                h2q[(size_t)px * 256 + co] = __float2bfloat16(rintf(fminf(h, 1.f) * ascale));
            }
        }
}

// ================= conv3: 1x1 256->1024, LDS-staged MFMA =================
// grid (2 M-half, 4 N(256co), 32); wave = 7 M-frags x 4 N-frags (64co)
__global__ __launch_bounds__(256) void conv3_mfma(
        char* wsb, const int* __restrict__ mask, float* __restrict__ out) {
    int b = blockIdx.z;
    int e = mask[b];
    float ascale = e_ascale(e), nq = e_nq(e);
    float s3 = __uint_as_float(((const unsigned*)(wsb + BO_WMAX))[2]) + 1e-12f;
    float kscale = (s3 / nq) / ascale;

    const short* h2q = (const short*)(wsb + BO_H2Q) + (size_t)b * 196 * 256;
    const short* w3q = (const short*)(wsb + BO_W3Q) + (size_t)e * 1024 * 256;
    float* ob = out + (size_t)b * 1024 * 196;

    __shared__ short As[112 * 72];
    __shared__ short Bs[256 * 72];

    int tid = threadIdx.x, w = tid >> 6, lane = tid & 63, r15 = lane & 15, g = lane >> 4;
    int px0 = blockIdx.x * 112;
    int coQ = blockIdx.y * 256;
    int cow = coQ + w * 64;
    const short8 z8 = {0, 0, 0, 0, 0, 0, 0, 0};

    f32x4 acc[7][4] = {};

    for (int k0 = 0; k0 < 256; k0 += 64) {
        __syncthreads();
        #pragma unroll
        for (int it = 0; it < 4; ++it) {             // A: 896 chunks
            int idx = it * 256 + tid;
            if (idx < 896) {
                int px = idx >> 3, c = idx & 7;
                short8 v = z8;
                if (px0 + px < 196) v = *(const short8*)(h2q + (size_t)(px0 + px) * 256 + k0 + c * 8);
                *(short8*)(As + px * 72 + c * 8) = v;
            }
        }
        #pragma unroll
        for (int it = 0; it < 8; ++it) {             // B: 256*8 = 2048 chunks
            int idx = it * 256 + tid;
            int co = idx >> 3, c = idx & 7;
            *(short8*)(Bs + co * 72 + c * 8) =
                *(const short8*)(w3q + (size_t)(coQ + co) * 256 + k0 + c * 8);
        }
        __syncthreads();
        #pragma unroll
        for (int ks = 0; ks < 2; ++ks) {
            short8 bf[4];
            #pragma unroll
            for (int n = 0; n < 4; ++n)
                bf[n] = *(const short8*)(Bs + (w * 64 + n * 16 + r15) * 72 + ks * 32 + g * 8);
            #pragma unroll
            for (int m = 0; m < 7; ++m) {
                short8 af = *(const short8*)(As + (m * 16 + r15) * 72 + ks * 32 + g * 8);
                #pragma unroll
                for (int n = 0; n < 4; ++n)
                    acc[m][n] = mfma16(af, bf[n], acc[m][n]);
            }
        }
    }
    #pragma unroll
    for (int n = 0; n < 4; ++n) {
        int co = cow + n * 16 + r15;
        #pragma unroll
        for (int m = 0; m < 7; ++m)
            #pragma unroll
            for (int r = 0; r < 4; ++r) {
                int px = px0 + m * 16 + g * 4 + r;
                if (px < 196)
                    ob[(size_t)co * 196 + px] = acc[m][n][r] * kscale;
            }
    }
}

// ---------------- GroupNorm(4) + affine + residual + ReLU (float4) ----------------
__global__ __launch_bounds__(256) void gn_kernel(
        float* __restrict__ out, const float* __restrict__ x,
        const float* __restrict__ gg, const float* __restrict__ gb) {
    int b = blockIdx.x >> 2, g = blockIdx.x & 3;
    const size_t boff = ((size_t)b * 1024 + g * 256) * PIX;
    float4* base = (float4*)(out + boff);
    const float4* xbase = (const float4*)(x + boff);

    int tid = threadIdx.x;
    float sum = 0.f, ssum = 0.f;
    for (int i = tid; i < 12544; i += 256) {         // 50176/4
        float4 v = base[i];
        sum += v.x + v.y + v.z + v.w;
        ssum += v.x * v.x + v.y * v.y + v.z * v.z + v.w * v.w;
    }
    __shared__ float rs[256], rss[256];
    rs[tid] = sum; rss[tid] = ssum;
    __syncthreads();
    for (int st = 128; st > 0; st >>= 1) {
        if (tid < st) { rs[tid] += rs[tid + st]; rss[tid] += rss[tid + st]; }
        __syncthreads();
    }
    float mu = rs[0] * (1.f / 50176.f);
    float var = rss[0] * (1.f / 50176.f) - mu * mu;
    float rstd = rsqrtf(var + EPSN);

    for (int i = tid; i < 12544; i += 256) {
        int gc = g * 256 + i / 49;                   // 196/4=49: float4 never crosses a channel
        float sc = gg[gc] * rstd;
        float sh = gb[gc] - mu * sc;
        float4 v = base[i];
        float4 xv = xbase[i];
        v.x = fmaxf(v.x * sc + sh + xv.x, 0.f);
        v.y = fmaxf(v.y * sc + sh + xv.y, 0.f);
        v.z = fmaxf(v.z * sc + sh + xv.z, 0.f);
        v.w = fmaxf(v.w * sc + sh + xv.w, 0.f);
        base[i] = v;
    }
}

// ---------------- launch ----------------
extern "C" void kernel_launch(void* const* d_in, const int* in_sizes, int n_in,
                              void* d_out, int out_size, void* d_ws, size_t ws_size,
                              hipStream_t stream) {
    (void)in_sizes; (void)n_in; (void)out_size; (void)ws_size;
    const float* x    = (const float*)d_in[0];
    const int*   mask = (const int*)d_in[1];
    const float* w1   = (const float*)d_in[2];
    const float* w2   = (const float*)d_in[3];
    const float* w3   = (const float*)d_in[4];
    const float* b1g  = (const float*)d_in[5];
    const float* b1b  = (const float*)d_in[6];
    const float* b1m  = (const float*)d_in[7];
    const float* b1v  = (const float*)d_in[8];
    const float* b2g  = (const float*)d_in[9];
    const float* b2b  = (const float*)d_in[10];
    const float* b2m  = (const float*)d_in[11];
    const float* b2v  = (const float*)d_in[12];
    const float* gng  = (const float*)d_in[13];
    const float* gnb  = (const float*)d_in[14];
    char* wsb = (char*)d_ws;
    float* out = (float*)d_out;
    unsigned* wmax = (unsigned*)(wsb + BO_WMAX);

    zero_kernel<<<1, 64, 0, stream>>>(wmax);
    maxabs_kernel<<<dim3(48, 3), 256, 0, stream>>>(w1, w2, w3, wmax);
    prepw_kernel<<<1024, 256, 0, stream>>>(w1, wsb, 0);
    prepx_kernel<<<dim3(16, 32), 256, 0, stream>>>(x, mask, wsb);
    conv1_mfma<<<dim3(2, 2, 32), 256, 0, stream>>>(wsb, mask, b1g, b1b, b1m, b1v);
    prepw_kernel<<<2304, 256, 0, stream>>>(w2, wsb, 1);   // overwrites dead xq region
    prepw_kernel<<<1024, 256, 0, stream>>>(w3, wsb, 2);
    conv2_mfma<<<dim3(2, 4, 32), 256, 0, stream>>>(wsb, mask, b2g, b2b, b2m, b2v);
    conv3_mfma<<<dim3(2, 4, 32), 256, 0, stream>>>(wsb, mask, out);
    gn_kernel<<<128, 256, 0, stream>>>(out, x, gng, gnb);
}

// Round 6
// 130.092 us; speedup vs baseline: 5.3723x; 1.2794x over previous
//
#include <hip/hip_runtime.h>
#include <hip/hip_bf16.h>

typedef __attribute__((ext_vector_type(8))) short short8;
typedef __attribute__((ext_vector_type(4))) float f32x4;

#define PIX  196
#define EPSN 1e-5f

// ---------------- workspace byte layout (~20.8 MB) ----------------
#define BO_WMAX 0
#define BO_XQ   256                      // [32][196][1024] bf16 = 12,845,056 B
#define BO_W2Q  BO_XQ                    // reuse after conv1: [3][9][256][256] bf16
#define BO_W3Q  (BO_XQ + 3538944)        // [3][1024][256] bf16
#define BO_H1Q  (BO_XQ + 12845056)       // [32][196][256] bf16
#define BO_H2Q  (BO_H1Q + 3211264)
#define BO_W1Q  (BO_H2Q + 3211264)       // [3][256][1024] bf16

__device__ __forceinline__ float e_ascale(int e) { return e == 0 ? 3.f : (e == 1 ? 15.f : 255.f); }
__device__ __forceinline__ float e_nq(int e)     { return e == 0 ? 1.f : (e == 1 ? 7.f : 127.f); }

__device__ __forceinline__ f32x4 mfma16(short8 a, short8 b, f32x4 c) {
    return __builtin_amdgcn_mfma_f32_16x16x32_bf16(a, b, c, 0, 0, 0);
}
__device__ __forceinline__ short bf16bits(float v) {
    __hip_bfloat16 h = __float2bfloat16(v);
    return *reinterpret_cast<short*>(&h);
}

// ---------------- zero wmax ----------------
__global__ void zero_kernel(unsigned* wmax) {
    if (threadIdx.x < 4) wmax[threadIdx.x] = 0u;
}

// ---------------- max|w| ----------------
__global__ __launch_bounds__(256) void maxabs_kernel(
        const float* __restrict__ w1, const float* __restrict__ w2,
        const float* __restrict__ w3, unsigned* __restrict__ wmax) {
    int t = blockIdx.y;
    const float* w = t == 0 ? w1 : (t == 1 ? w2 : w3);
    int n = (t == 1) ? 256 * 256 * 9 : 256 * 1024;
    float m = 0.f;
    for (int i = blockIdx.x * 256 + threadIdx.x; i < n; i += gridDim.x * 256)
        m = fmaxf(m, fabsf(w[i]));
    __shared__ float red[256];
    red[threadIdx.x] = m;
    __syncthreads();
    for (int s = 128; s > 0; s >>= 1) {
        if (threadIdx.x < s) red[threadIdx.x] = fmaxf(red[threadIdx.x], red[threadIdx.x + s]);
        __syncthreads();
    }
    if (threadIdx.x == 0) atomicMax(&wmax[t], __float_as_uint(red[0]));
}

// ---------------- weight -> integer bf16, 3 experts ----------------
__global__ __launch_bounds__(256) void prepw_kernel(
        const float* __restrict__ w, char* wsb, int which) {
    int n = (which == 1) ? 589824 : 262144;
    int idx = blockIdx.x * 256 + threadIdx.x;
    if (idx >= n) return;
    const unsigned* wmaxu = (const unsigned*)(wsb + BO_WMAX);
    float s = __uint_as_float(wmaxu[which]) + 1e-12f;
    float v = w[idx];
    __hip_bfloat16* dst;
    size_t off, estride;
    if (which == 0)      { dst = (__hip_bfloat16*)(wsb + BO_W1Q); off = idx; estride = 262144; }
    else if (which == 1) {
        int co = idx / 2304, r = idx - co * 2304, ci = r / 9, tap = r - ci * 9;
        dst = (__hip_bfloat16*)(wsb + BO_W2Q);
        off = ((size_t)tap * 256 + co) * 256 + ci; estride = 589824;
    } else               { dst = (__hip_bfloat16*)(wsb + BO_W3Q); off = idx; estride = 262144; }
    #pragma unroll
    for (int e = 0; e < 3; ++e) {
        float q = rintf(v / s * e_nq(e));            // integer in [-127,127]: exact in bf16
        dst[e * estride + off] = __float2bfloat16(q);
    }
}

// ---------------- x -> qact integer bf16, NCHW -> NHWC ----------------
__global__ __launch_bounds__(256) void prepx_kernel(
        const float* __restrict__ x, const int* __restrict__ mask, char* wsb) {
    int b = blockIdx.y, c0 = blockIdx.x * 64;
    float ascale = e_ascale(mask[b]);
    __shared__ float xs[64][197];
    int tid = threadIdx.x;
    for (int idx = tid; idx < 64 * 196; idx += 256) {
        int ci = idx / 196, p = idx - ci * 196;
        xs[ci][p] = x[((size_t)b * 1024 + c0 + ci) * 196 + p];
    }
    __syncthreads();
    __hip_bfloat16* xq = (__hip_bfloat16*)(wsb + BO_XQ);
    for (int idx = tid; idx < 196 * 64; idx += 256) {
        int p = idx / 64, ci = idx - p * 64;
        float v = fminf(fmaxf(xs[ci][p], 0.f), 1.f);
        xq[((size_t)b * 196 + p) * 1024 + c0 + ci] = __float2bfloat16(rintf(v * ascale));
    }
}

// ================= conv1: 1x1 1024->256, K-split partial GEMM =================
// grid (2 M, 8 = 4N*2K, 32). 4 waves, wave = 7M x 16co. Partials f32 -> P (d_out scratch).
__global__ __launch_bounds__(256) void conv1_mfma(
        char* wsb, const int* __restrict__ mask, float* __restrict__ P) {
    int b = blockIdx.z;
    int e = mask[b];
    int ntile = blockIdx.y >> 1, kh = blockIdx.y & 1;
    const short* xq  = (const short*)(wsb + BO_XQ) + (size_t)b * 196 * 1024;
    const short* w1q = (const short*)(wsb + BO_W1Q) + (size_t)e * 256 * 1024;

    __shared__ short As[112 * 72];
    __shared__ short Bs[64 * 72];

    int tid = threadIdx.x, w = tid >> 6, lane = tid & 63, r15 = lane & 15, g = lane >> 4;
    int px0 = blockIdx.x * 112;
    int coB = ntile * 64;
    int kbase = kh * 512;

    const short8 z8 = {0, 0, 0, 0, 0, 0, 0, 0};
    short8 ra[4], rb[2];

    auto load_tile = [&](int t) {
        int k0 = kbase + t * 64;
        #pragma unroll
        for (int it = 0; it < 4; ++it) {
            int idx = it * 256 + tid;
            ra[it] = z8;
            if (idx < 896) {
                int px = idx >> 3, c = idx & 7;
                if (px0 + px < 196)
                    ra[it] = *(const short8*)(xq + (size_t)(px0 + px) * 1024 + k0 + c * 8);
            }
        }
        #pragma unroll
        for (int it = 0; it < 2; ++it) {
            int idx = it * 256 + tid;
            int co = idx >> 3, c = idx & 7;
            rb[it] = *(const short8*)(w1q + (size_t)(coB + co) * 1024 + k0 + c * 8);
        }
    };
    auto store_tile = [&]() {
        #pragma unroll
        for (int it = 0; it < 4; ++it) {
            int idx = it * 256 + tid;
            if (idx < 896) {
                int px = idx >> 3, c = idx & 7;
                *(short8*)(As + px * 72 + c * 8) = ra[it];
            }
        }
        #pragma unroll
        for (int it = 0; it < 2; ++it) {
            int idx = it * 256 + tid;
            int co = idx >> 3, c = idx & 7;
            *(short8*)(Bs + co * 72 + c * 8) = rb[it];
        }
    };

    f32x4 acc[7] = {};
    load_tile(0);
    for (int t = 0; t < 8; ++t) {
        __syncthreads();
        store_tile();
        __syncthreads();
        if (t < 7) load_tile(t + 1);
        #pragma unroll
        for (int ks = 0; ks < 2; ++ks) {
            short8 bf = *(const short8*)(Bs + (w * 16 + r15) * 72 + ks * 32 + g * 8);
            #pragma unroll
            for (int m = 0; m < 7; ++m) {
                short8 af = *(const short8*)(As + (m * 16 + r15) * 72 + ks * 32 + g * 8);
                acc[m] = mfma16(af, bf, acc[m]);
            }
        }
    }
    float* Pp = P + (size_t)kh * 32 * 196 * 256 + (size_t)b * 196 * 256;
    int co = coB + w * 16 + r15;
    #pragma unroll
    for (int m = 0; m < 7; ++m)
        #pragma unroll
        for (int r = 0; r < 4; ++r) {
            int px = px0 + m * 16 + g * 4 + r;
            if (px < 196) Pp[(size_t)px * 256 + co] = acc[m][r];
        }
}

// ---------------- reduce partials + BN + ReLU + qact -> h1q/h2q ----------------
__global__ __launch_bounds__(256) void reducebn_kernel(
        const float* __restrict__ P, char* wsb, const int* __restrict__ mask,
        const float* __restrict__ bg, const float* __restrict__ bb,
        const float* __restrict__ bm, const float* __restrict__ bv, int which) {
    __hip_bfloat16* dst = (__hip_bfloat16*)(wsb + (which ? BO_H2Q : BO_H1Q));
    float s = __uint_as_float(((const unsigned*)(wsb + BO_WMAX))[which]) + 1e-12f;
    int tid = blockIdx.x * 256 + threadIdx.x;
    const int total = 32 * 196 * 64;                 // float4 groups
    for (int idx = tid; idx < total; idx += gridDim.x * 256) {
        int b = idx / (196 * 64);
        int rem = idx - b * (196 * 64);
        int px = rem >> 6, co = (rem & 63) * 4;
        int e = mask[b];
        float ascale = e_ascale(e);
        float kscale = (s / e_nq(e)) / ascale;
        size_t o = ((size_t)b * 196 + px) * 256 + co;
        float4 p0 = *(const float4*)(P + o);
        float4 p1 = *(const float4*)(P + (size_t)32 * 196 * 256 + o);
        float4 gv = *(const float4*)(bg + co);
        float4 bbv = *(const float4*)(bb + co);
        float4 mv = *(const float4*)(bm + co);
        float4 vv = *(const float4*)(bv + co);
        float r[4] = {p0.x + p1.x, p0.y + p1.y, p0.z + p1.z, p0.w + p1.w};
        float gg[4] = {gv.x, gv.y, gv.z, gv.w}, bbs[4] = {bbv.x, bbv.y, bbv.z, bbv.w};
        float mm[4] = {mv.x, mv.y, mv.z, mv.w}, vvs[4] = {vv.x, vv.y, vv.z, vv.w};
        short4 q;
        short* qp = (short*)&q;
        #pragma unroll
        for (int j = 0; j < 4; ++j) {
            float inv = gg[j] * rsqrtf(vvs[j] + EPSN);
            float h = fmaxf(r[j] * (kscale * inv) + (bbs[j] - mm[j] * inv), 0.f);
            qp[j] = bf16bits(rintf(fminf(h, 1.f) * ascale));
        }
        *(short4*)(dst + o) = q;
    }
}

// ================= conv2: 3x3 256->256, K-split padded-patch MFMA =================
// grid (2 M, 8 = 4N*2K, 32). 4 waves, wave = 7M x 16co.
__global__ __launch_bounds__(256) void conv2_mfma(
        char* wsb, const int* __restrict__ mask, float* __restrict__ P) {
    int b = blockIdx.z;
    int e = mask[b];
    int ntile = blockIdx.y >> 1, kh = blockIdx.y & 1;
    const short* h1q = (const short*)(wsb + BO_H1Q) + (size_t)b * 196 * 256;
    const short* w2q = (const short*)(wsb + BO_W2Q) + (size_t)e * 589824;

    __shared__ short Xs[16 * 16 * 32];   // padded patch [sy][sx][32ci], 16 KB
    __shared__ short Ws9[9 * 64 * 32];   // [tap][co][32ci], 36 KB

    int tid = threadIdx.x, w = tid >> 6, lane = tid & 63, r15 = lane & 15, g = lane >> 4;
    int px0 = blockIdx.x * 112;
    int coB = ntile * 64;
    int cibase = kh * 128;
    const short8 z8 = {0, 0, 0, 0, 0, 0, 0, 0};

    short8 rx[4], rw[9];
    auto load_tile = [&](int sl) {
        int ci0 = cibase + sl * 32;
        #pragma unroll
        for (int it = 0; it < 4; ++it) {
            int idx = it * 256 + tid;
            if (idx < 784) {
                int px = idx >> 2, c = idx & 3;
                rx[it] = *(const short8*)(h1q + (size_t)px * 256 + ci0 + c * 8);
            }
        }
        #pragma unroll
        for (int it = 0; it < 9; ++it) {
            int idx = it * 256 + tid;
            int tap = idx >> 8, rem = idx & 255, co = rem >> 2, c = rem & 3;
            rw[it] = *(const short8*)(w2q + ((size_t)tap * 256 + coB + co) * 256 + ci0 + c * 8);
        }
    };
    auto store_tile = [&]() {
        #pragma unroll
        for (int it = 0; it < 4; ++it) {
            int idx = it * 256 + tid;
            if (idx < 784) {
                int px = idx >> 2, c = idx & 3;
                int y = px / 14, xx = px - y * 14;
                *(short8*)(Xs + ((y + 1) * 16 + (xx + 1)) * 32 + c * 8) = rx[it];
            }
        }
        #pragma unroll
        for (int it = 0; it < 9; ++it) {
            int idx = it * 256 + tid;
            int tap = idx >> 8, rem = idx & 255, co = rem >> 2, c = rem & 3;
            *(short8*)(Ws9 + (tap * 64 + co) * 32 + c * 8) = rw[it];
        }
    };

    // zero halo border once (interior writes never touch it)
    if (tid < 240) {
        int bp = tid >> 2, c = tid & 3;
        int sy, sx;
        if (bp < 16)      { sy = 0;       sx = bp; }
        else if (bp < 32) { sy = 15;      sx = bp - 16; }
        else if (bp < 46) { sy = bp - 31; sx = 0; }
        else              { sy = bp - 45; sx = 15; }
        *(short8*)(Xs + (sy * 16 + sx) * 32 + c * 8) = z8;
    }

    f32x4 acc[7] = {};
    load_tile(0);
    for (int sl = 0; sl < 4; ++sl) {
        __syncthreads();
        store_tile();
        __syncthreads();
        if (sl < 3) load_tile(sl + 1);
        #pragma unroll
        for (int tap = 0; tap < 9; ++tap) {
            short8 bf = *(const short8*)(Ws9 + (tap * 64 + w * 16 + r15) * 32 + g * 8);
            int ty = tap / 3, tx = tap - ty * 3;
            #pragma unroll
            for (int m = 0; m < 7; ++m) {
                int px = px0 + m * 16 + r15;
                int ap = min(px, 195);
                int y = ap / 14, xx = ap - y * 14;
                short8 af = *(const short8*)(Xs + ((y + ty) * 16 + (xx + tx)) * 32 + g * 8);
                acc[m] = mfma16(af, bf, acc[m]);
            }
        }
    }
    float* Pp = P + (size_t)kh * 32 * 196 * 256 + (size_t)b * 196 * 256;
    int co = coB + w * 16 + r15;
    #pragma unroll
    for (int m = 0; m < 7; ++m)
        #pragma unroll
        for (int r = 0; r < 4; ++r) {
            int px = px0 + m * 16 + g * 4 + r;
            if (px < 196) Pp[(size_t)px * 256 + co] = acc[m][r];
        }
}

// ================= conv3: 1x1 256->1024, f32 NCHW -> d_out =================
// grid (2 M, 8 N, 32). 4 waves, wave = 7M x 2N(32co).
__global__ __launch_bounds__(256) void conv3_mfma(
        char* wsb, const int* __restrict__ mask, float* __restrict__ out) {
    int b = blockIdx.z;
    int e = mask[b];
    float ascale = e_ascale(e), nq = e_nq(e);
    float s3 = __uint_as_float(((const unsigned*)(wsb + BO_WMAX))[2]) + 1e-12f;
    float kscale = (s3 / nq) / ascale;

    const short* h2q = (const short*)(wsb + BO_H2Q) + (size_t)b * 196 * 256;
    const short* w3q = (const short*)(wsb + BO_W3Q) + (size_t)e * 1024 * 256;
    float* ob = out + (size_t)b * 1024 * 196;

    __shared__ short As[112 * 72];
    __shared__ short Bs[128 * 72];

    int tid = threadIdx.x, w = tid >> 6, lane = tid & 63, r15 = lane & 15, g = lane >> 4;
    int px0 = blockIdx.x * 112;
    int coQ = blockIdx.y * 128;
    const short8 z8 = {0, 0, 0, 0, 0, 0, 0, 0};

    short8 ra[4], rb[4];
    auto load_tile = [&](int t) {
        int k0 = t * 64;
        #pragma unroll
        for (int it = 0; it < 4; ++it) {
            int idx = it * 256 + tid;
            ra[it] = z8;
            if (idx < 896) {
                int px = idx >> 3, c = idx & 7;
                if (px0 + px < 196)
                    ra[it] = *(const short8*)(h2q + (size_t)(px0 + px) * 256 + k0 + c * 8);
            }
        }
        #pragma unroll
        for (int it = 0; it < 4; ++it) {
            int idx = it * 256 + tid;
            int co = idx >> 3, c = idx & 7;
            rb[it] = *(const short8*)(w3q + (size_t)(coQ + co) * 256 + k0 + c * 8);
        }
    };
    auto store_tile = [&]() {
        #pragma unroll
        for (int it = 0; it < 4; ++it) {
            int idx = it * 256 + tid;
            if (idx < 896) {
                int px = idx >> 3, c = idx & 7;
                *(short8*)(As + px * 72 + c * 8) = ra[it];
            }
        }
        #pragma unroll
        for (int it = 0; it < 4; ++it) {
            int idx = it * 256 + tid;
            int co = idx >> 3, c = idx & 7;
            *(short8*)(Bs + co * 72 + c * 8) = rb[it];
        }
    };

    f32x4 acc[7][2] = {};
    load_tile(0);
    for (int t = 0; t < 4; ++t) {
        __syncthreads();
        store_tile();
        __syncthreads();
        if (t < 3) load_tile(t + 1);
        #pragma unroll
        for (int ks = 0; ks < 2; ++ks) {
            short8 bf0 = *(const short8*)(Bs + (w * 32 + r15) * 72 + ks * 32 + g * 8);
            short8 bf1 = *(const short8*)(Bs + (w * 32 + 16 + r15) * 72 + ks * 32 + g * 8);
            #pragma unroll
            for (int m = 0; m < 7; ++m) {
                short8 af = *(const short8*)(As + (m * 16 + r15) * 72 + ks * 32 + g * 8);
                acc[m][0] = mfma16(af, bf0, acc[m][0]);
                acc[m][1] = mfma16(af, bf1, acc[m][1]);
            }
        }
    }
    #pragma unroll
    for (int n = 0; n < 2; ++n) {
        int co = coQ + w * 32 + n * 16 + r15;
        #pragma unroll
        for (int m = 0; m < 7; ++m)
            #pragma unroll
            for (int r = 0; r < 4; ++r) {
                int px = px0 + m * 16 + g * 4 + r;
                if (px < 196)
                    ob[(size_t)co * 196 + px] = acc[m][n][r] * kscale;
            }
    }
}

// ---------------- GroupNorm(4) + affine + residual + ReLU (float4, 1024 thr) ----------------
__global__ __launch_bounds__(1024) void gn_kernel(
        float* __restrict__ out, const float* __restrict__ x,
        const float* __restrict__ gg, const float* __restrict__ gb) {
    int b = blockIdx.x >> 2, g = blockIdx.x & 3;
    const size_t boff = ((size_t)b * 1024 + g * 256) * PIX;
    float4* base = (float4*)(out + boff);
    const float4* xbase = (const float4*)(x + boff);

    int tid = threadIdx.x;
    float sum = 0.f, ssum = 0.f;
    for (int i = tid; i < 12544; i += 1024) {
        float4 v = base[i];
        sum += v.x + v.y + v.z + v.w;
        ssum += v.x * v.x + v.y * v.y + v.z * v.z + v.w * v.w;
    }
    __shared__ float rs[1024], rss[1024];
    rs[tid] = sum; rss[tid] = ssum;
    __syncthreads();
    for (int st = 512; st > 0; st >>= 1) {
        if (tid < st) { rs[tid] += rs[tid + st]; rss[tid] += rss[tid + st]; }
        __syncthreads();
    }
    float mu = rs[0] * (1.f / 50176.f);
    float var = rss[0] * (1.f / 50176.f) - mu * mu;
    float rstd = rsqrtf(var + EPSN);

    for (int i = tid; i < 12544; i += 1024) {
        int gc = g * 256 + i / 49;
        float sc = gg[gc] * rstd;
        float sh = gb[gc] - mu * sc;
        float4 v = base[i];
        float4 xv = xbase[i];
        v.x = fmaxf(v.x * sc + sh + xv.x, 0.f);
        v.y = fmaxf(v.y * sc + sh + xv.y, 0.f);
        v.z = fmaxf(v.z * sc + sh + xv.z, 0.f);
        v.w = fmaxf(v.w * sc + sh + xv.w, 0.f);
        base[i] = v;
    }
}

// ---------------- launch ----------------
extern "C" void kernel_launch(void* const* d_in, const int* in_sizes, int n_in,
                              void* d_out, int out_size, void* d_ws, size_t ws_size,
                              hipStream_t stream) {
    (void)in_sizes; (void)n_in; (void)out_size; (void)ws_size;
    const float* x    = (const float*)d_in[0];
    const int*   mask = (const int*)d_in[1];
    const float* w1   = (const float*)d_in[2];
    const float* w2   = (const float*)d_in[3];
    const float* w3   = (const float*)d_in[4];
    const float* b1g  = (const float*)d_in[5];
    const float* b1b  = (const float*)d_in[6];
    const float* b1m  = (const float*)d_in[7];
    const float* b1v  = (const float*)d_in[8];
    const float* b2g  = (const float*)d_in[9];
    const float* b2b  = (const float*)d_in[10];
    const float* b2m  = (const float*)d_in[11];
    const float* b2v  = (const float*)d_in[12];
    const float* gng  = (const float*)d_in[13];
    const float* gnb  = (const float*)d_in[14];
    char* wsb = (char*)d_ws;
    float* out = (float*)d_out;
    unsigned* wmax = (unsigned*)(wsb + BO_WMAX);

    zero_kernel<<<1, 64, 0, stream>>>(wmax);
    maxabs_kernel<<<dim3(48, 3), 256, 0, stream>>>(w1, w2, w3, wmax);
    prepw_kernel<<<1024, 256, 0, stream>>>(w1, wsb, 0);
    prepx_kernel<<<dim3(16, 32), 256, 0, stream>>>(x, mask, wsb);
    conv1_mfma<<<dim3(2, 8, 32), 256, 0, stream>>>(wsb, mask, out);           // partials in d_out
    prepw_kernel<<<2304, 256, 0, stream>>>(w2, wsb, 1);                       // overwrites dead xq
    prepw_kernel<<<1024, 256, 0, stream>>>(w3, wsb, 2);
    reducebn_kernel<<<512, 256, 0, stream>>>(out, wsb, mask, b1g, b1b, b1m, b1v, 0);
    conv2_mfma<<<dim3(2, 8, 32), 256, 0, stream>>>(wsb, mask, out);           // partials in d_out
    reducebn_kernel<<<512, 256, 0, stream>>>(out, wsb, mask, b2g, b2b, b2m, b2v, 1);
    conv3_mfma<<<dim3(2, 8, 32), 256, 0, stream>>>(wsb, mask, out);           // final f32 NCHW
    gn_kernel<<<128, 1024, 0, stream>>>(out, x, gng, gnb);
}

// Round 7
// 116.755 us; speedup vs baseline: 5.9859x; 1.1142x over previous
//
#include <hip/hip_runtime.h>
#include <hip/hip_bf16.h>

typedef __attribute__((ext_vector_type(8))) short short8;
typedef __attribute__((ext_vector_type(4))) float f32x4;

#define PIX  196
#define EPSN 1e-5f

// ---------------- workspace byte layout (~20.85 MB, proven size range) ----------------
#define BO_XQ   256                      // [32][196][1024] bf16 = 12,845,056 B
#define BO_W2Q  BO_XQ                    // reuse after conv1: [3][9][256][256] bf16
#define BO_W3Q  (BO_XQ + 3538944)        // [3][1024][256] bf16
#define BO_H1Q  (BO_XQ + 12845056)       // [32][196][256] bf16
#define BO_H2Q  (BO_H1Q + 3211264)
#define BO_W1Q  (BO_H2Q + 3211264)       // [3][256][1024] bf16
#define BO_GNS  (BO_W1Q + 1572864)       // [128][4][2] f32 = 4 KB
#define BO_PMAX (BO_GNS + 4096)          // [3][48] f32

__device__ __forceinline__ float e_ascale(int e) { return e == 0 ? 3.f : (e == 1 ? 15.f : 255.f); }
__device__ __forceinline__ float e_nq(int e)     { return e == 0 ? 1.f : (e == 1 ? 7.f : 127.f); }

__device__ __forceinline__ f32x4 mfma16(short8 a, short8 b, f32x4 c) {
    return __builtin_amdgcn_mfma_f32_16x16x32_bf16(a, b, c, 0, 0, 0);
}
__device__ __forceinline__ float wmax_reduce(const char* wsb, int t) {
    const float* pm = (const float*)(wsb + BO_PMAX) + t * 48;
    float s = 0.f;
    #pragma unroll
    for (int k = 0; k < 48; ++k) s = fmaxf(s, pm[k]);
    return s + 1e-12f;
}

// ---------------- max|w| partials: [3][48] ----------------
__global__ __launch_bounds__(256) void maxabs_kernel(
        const float* __restrict__ w1, const float* __restrict__ w2,
        const float* __restrict__ w3, float* __restrict__ pmax) {
    int t = blockIdx.y;
    const float* w = t == 0 ? w1 : (t == 1 ? w2 : w3);
    int n = (t == 1) ? 256 * 256 * 9 : 256 * 1024;
    float m = 0.f;
    for (int i = blockIdx.x * 256 + threadIdx.x; i < n; i += 48 * 256)
        m = fmaxf(m, fabsf(w[i]));
    __shared__ float red[256];
    red[threadIdx.x] = m;
    __syncthreads();
    for (int s = 128; s > 0; s >>= 1) {
        if (threadIdx.x < s) red[threadIdx.x] = fmaxf(red[threadIdx.x], red[threadIdx.x + s]);
        __syncthreads();
    }
    if (threadIdx.x == 0) pmax[t * 48 + blockIdx.x] = red[0];
}

// ---------------- w1 -> integer bf16 [e][co][ci] ----------------
__global__ __launch_bounds__(256) void prepw1_kernel(const float* __restrict__ w, char* wsb) {
    int idx = blockIdx.x * 256 + threadIdx.x;           // 262144 exactly
    float s = wmax_reduce(wsb, 0);
    float v = w[idx];
    __hip_bfloat16* dst = (__hip_bfloat16*)(wsb + BO_W1Q);
    #pragma unroll
    for (int e = 0; e < 3; ++e)
        dst[e * 262144 + idx] = __float2bfloat16(rintf(v / s * e_nq(e)));
}

// ---------------- w2,w3 -> integer bf16 (after conv1; overwrites dead xq) ----------------
__global__ __launch_bounds__(256) void prepw23_kernel(
        const float* __restrict__ w2, const float* __restrict__ w3, char* wsb) {
    int idx = blockIdx.x * 256 + threadIdx.x;           // 851968 = 589824 + 262144
    if (idx < 589824) {
        float s = wmax_reduce(wsb, 1);
        float v = w2[idx];
        int co = idx / 2304, r = idx - co * 2304, ci = r / 9, tap = r - ci * 9;
        __hip_bfloat16* dst = (__hip_bfloat16*)(wsb + BO_W2Q);
        size_t off = ((size_t)tap * 256 + co) * 256 + ci;
        #pragma unroll
        for (int e = 0; e < 3; ++e)
            dst[e * 589824 + off] = __float2bfloat16(rintf(v / s * e_nq(e)));
    } else {
        int i2 = idx - 589824;
        float s = wmax_reduce(wsb, 2);
        float v = w3[i2];
        __hip_bfloat16* dst = (__hip_bfloat16*)(wsb + BO_W3Q);
        #pragma unroll
        for (int e = 0; e < 3; ++e)
            dst[e * 262144 + i2] = __float2bfloat16(rintf(v / s * e_nq(e)));
    }
}

// ---------------- x -> qact integer bf16, NCHW -> NHWC ----------------
__global__ __launch_bounds__(256) void prepx_kernel(
        const float* __restrict__ x, const int* __restrict__ mask, char* wsb) {
    int b = blockIdx.y, c0 = blockIdx.x * 64;
    float ascale = e_ascale(mask[b]);
    __shared__ float xs[64][197];
    int tid = threadIdx.x;
    for (int idx = tid; idx < 64 * 196; idx += 256) {
        int ci = idx / 196, p = idx - ci * 196;
        xs[ci][p] = x[((size_t)b * 1024 + c0 + ci) * 196 + p];
    }
    __syncthreads();
    __hip_bfloat16* xq = (__hip_bfloat16*)(wsb + BO_XQ);
    for (int idx = tid; idx < 196 * 64; idx += 256) {
        int p = idx / 64, ci = idx - p * 64;
        float v = fminf(fmaxf(xs[ci][p], 0.f), 1.f);
        xq[((size_t)b * 196 + p) * 1024 + c0 + ci] = __float2bfloat16(rintf(v * ascale));
    }
}

// ================= conv1: 1x1 1024->256 + BN1 + ReLU + qact =================
// grid (7 M(28px), 4 N(64co), 32). 4 waves; wave = 2 M-frags x 16co, K=1024.
__global__ __launch_bounds__(256) void conv1_mfma(
        char* wsb, const int* __restrict__ mask,
        const float* __restrict__ bg, const float* __restrict__ bb,
        const float* __restrict__ bm, const float* __restrict__ bv) {
    int b = blockIdx.z;
    int e = mask[b];
    float ascale = e_ascale(e);
    float s1 = wmax_reduce(wsb, 0);
    float kscale = (s1 / e_nq(e)) / ascale;

    const short* xq  = (const short*)(wsb + BO_XQ) + (size_t)b * 196 * 1024;
    const short* w1q = (const short*)(wsb + BO_W1Q) + (size_t)e * 256 * 1024;
    __hip_bfloat16* h1q = (__hip_bfloat16*)(wsb + BO_H1Q) + (size_t)b * 196 * 256;

    __shared__ short As[32 * 72];
    __shared__ short Bs[64 * 72];

    int tid = threadIdx.x, w = tid >> 6, lane = tid & 63, r15 = lane & 15, g = lane >> 4;
    int px0 = blockIdx.x * 28;
    int coB = blockIdx.y * 64;

    int arow = tid >> 3, ac8 = (tid & 7) * 8;
    const short* aptr = xq + (size_t)min(px0 + arow, 195) * 1024 + ac8;
    const short* bptr0 = w1q + (size_t)(coB + arow) * 1024 + ac8;
    const short* bptr1 = bptr0 + (size_t)32 * 1024;

    short8 ra, rb0, rb1;
    auto load_tile = [&](int t) {
        int k0 = t * 64;
        ra  = *(const short8*)(aptr + k0);
        rb0 = *(const short8*)(bptr0 + k0);
        rb1 = *(const short8*)(bptr1 + k0);
    };
    auto store_tile = [&]() {
        *(short8*)(As + arow * 72 + ac8) = ra;
        *(short8*)(Bs + arow * 72 + ac8) = rb0;
        *(short8*)(Bs + (32 + arow) * 72 + ac8) = rb1;
    };

    f32x4 acc[2] = {};
    load_tile(0);
    for (int t = 0; t < 16; ++t) {
        __syncthreads();
        store_tile();
        __syncthreads();
        if (t < 15) load_tile(t + 1);
        #pragma unroll
        for (int ks = 0; ks < 2; ++ks) {
            short8 bf = *(const short8*)(Bs + (w * 16 + r15) * 72 + ks * 32 + g * 8);
            #pragma unroll
            for (int m = 0; m < 2; ++m) {
                short8 af = *(const short8*)(As + (m * 16 + r15) * 72 + ks * 32 + g * 8);
                acc[m] = mfma16(af, bf, acc[m]);
            }
        }
    }
    int co = coB + w * 16 + r15;
    float inv = bg[co] * rsqrtf(bv[co] + EPSN);
    float mm = kscale * inv;
    float beta = bb[co] - bm[co] * inv;
    #pragma unroll
    for (int m = 0; m < 2; ++m)
        #pragma unroll
        for (int r = 0; r < 4; ++r) {
            int s = m * 16 + g * 4 + r;
            if (s < 28) {
                float h = fmaxf(acc[m][r] * mm + beta, 0.f);
                h1q[(size_t)(px0 + s) * 256 + co] = __float2bfloat16(rintf(fminf(h, 1.f) * ascale));
            }
        }
}

// ================= conv2: 3x3 256->256 + BN2 + ReLU + qact =================
// grid (7 row-pairs, 4 N(64co), 32). 4 waves; wave = 2 M-frags x 16co.
__global__ __launch_bounds__(256) void conv2_mfma(
        char* wsb, const int* __restrict__ mask,
        const float* __restrict__ bg, const float* __restrict__ bb,
        const float* __restrict__ bm, const float* __restrict__ bv) {
    int b = blockIdx.z;
    int e = mask[b];
    float ascale = e_ascale(e);
    float s2 = wmax_reduce(wsb, 1);
    float kscale = (s2 / e_nq(e)) / ascale;

    const short* h1q = (const short*)(wsb + BO_H1Q) + (size_t)b * 196 * 256;
    const short* w2q = (const short*)(wsb + BO_W2Q) + (size_t)e * 589824;
    __hip_bfloat16* h2q = (__hip_bfloat16*)(wsb + BO_H2Q) + (size_t)b * 196 * 256;

    __shared__ short Xs[4 * 16 * 40];    // input rows r0-1..r0+2, cols -1..14, 32ci (stride 40)
    __shared__ short Ws9[9 * 64 * 40];   // [tap][co][32ci] (stride 40)

    int tid = threadIdx.x, w = tid >> 6, lane = tid & 63, r15 = lane & 15, g = lane >> 4;
    int r0 = blockIdx.x * 2;
    int px0 = blockIdx.x * 28;
    int coB = blockIdx.y * 64;
    const short8 z8 = {0, 0, 0, 0, 0, 0, 0, 0};

    // per-thread X staging coords: 4x16x4 = 256 chunks exactly
    int xc = tid & 3, xsx = (tid >> 2) & 15, xsy = tid >> 6;
    int iy = r0 - 1 + xsy, ix = xsx - 1;
    bool xvalid = ((unsigned)iy < 14u) && ((unsigned)ix < 14u);
    const short* xsrc = h1q + (size_t)(iy * 14 + ix) * 256 + xc * 8;
    // per-thread W staging coords: tap = it, co = tid>>2, c = tid&3
    int wco = tid >> 2, wc8 = (tid & 3) * 8;

    // per-m A coords
    int rr[2], cc[2];
    #pragma unroll
    for (int m = 0; m < 2; ++m) {
        int s0 = min(m * 16 + r15, 27);
        rr[m] = s0 / 14; cc[m] = s0 - rr[m] * 14;
    }

    short8 rx, rw[9];
    auto load_tile = [&](int sl) {
        int ci0 = sl * 32;
        rx = xvalid ? *(const short8*)(xsrc + ci0) : z8;
        #pragma unroll
        for (int tap = 0; tap < 9; ++tap)
            rw[tap] = *(const short8*)(w2q + ((size_t)tap * 256 + coB + wco) * 256 + ci0 + wc8);
    };
    auto store_tile = [&]() {
        *(short8*)(Xs + (xsy * 16 + xsx) * 40 + xc * 8) = rx;
        #pragma unroll
        for (int tap = 0; tap < 9; ++tap)
            *(short8*)(Ws9 + (tap * 64 + wco) * 40 + wc8) = rw[tap];
    };

    f32x4 acc[2] = {};
    load_tile(0);
    for (int sl = 0; sl < 8; ++sl) {
        __syncthreads();
        store_tile();
        __syncthreads();
        if (sl < 7) load_tile(sl + 1);
        #pragma unroll
        for (int tap = 0; tap < 9; ++tap) {
            int ty = tap / 3, tx = tap - ty * 3;
            short8 bf = *(const short8*)(Ws9 + (tap * 64 + w * 16 + r15) * 40 + g * 8);
            #pragma unroll
            for (int m = 0; m < 2; ++m) {
                short8 af = *(const short8*)(Xs + ((rr[m] + ty) * 16 + cc[m] + tx) * 40 + g * 8);
                acc[m] = mfma16(af, bf, acc[m]);
            }
        }
    }
    int co = coB + w * 16 + r15;
    float inv = bg[co] * rsqrtf(bv[co] + EPSN);
    float mm = kscale * inv;
    float beta = bb[co] - bm[co] * inv;
    #pragma unroll
    for (int m = 0; m < 2; ++m)
        #pragma unroll
        for (int r = 0; r < 4; ++r) {
            int s = m * 16 + g * 4 + r;
            if (s < 28) {
                float h = fmaxf(acc[m][r] * mm + beta, 0.f);
                h2q[(size_t)(px0 + s) * 256 + co] = __float2bfloat16(rintf(fminf(h, 1.f) * ascale));
            }
        }
}

// ================= conv3: 1x1 256->1024, LDS-transposed coalesced f32 store =================
// grid (7 M(28px), 8 N(128co), 32). 4 waves; wave = 2 M x 2 N frags.
__global__ __launch_bounds__(256) void conv3_mfma(
        char* wsb, const int* __restrict__ mask, float* __restrict__ out) {
    int b = blockIdx.z;
    int e = mask[b];
    float ascale = e_ascale(e);
    float s3 = wmax_reduce(wsb, 2);
    float kscale = (s3 / e_nq(e)) / ascale;

    const short* h2q = (const short*)(wsb + BO_H2Q) + (size_t)b * 196 * 256;
    const short* w3q = (const short*)(wsb + BO_W3Q) + (size_t)e * 1024 * 256;
    float* ob = out + (size_t)b * 1024 * 196;

    __shared__ short smem[32 * 72 + 128 * 72];   // As | Bs ; reused as Ct f32 [128][30]
    short* As = smem;
    short* Bs = smem + 32 * 72;

    int tid = threadIdx.x, w = tid >> 6, lane = tid & 63, r15 = lane & 15, g = lane >> 4;
    int px0 = blockIdx.x * 28;
    int coQ = blockIdx.y * 128;

    int arow = tid >> 3, ac8 = (tid & 7) * 8;
    const short* aptr = h2q + (size_t)min(px0 + arow, 195) * 256 + ac8;
    const short* bptr = w3q + (size_t)(coQ + arow) * 256 + ac8;

    short8 ra, rb[4];
    auto load_tile = [&](int t) {
        int k0 = t * 64;
        ra = *(const short8*)(aptr + k0);
        #pragma unroll
        for (int it = 0; it < 4; ++it)
            rb[it] = *(const short8*)(bptr + (size_t)it * 32 * 256 + k0);
    };
    auto store_tile = [&]() {
        *(short8*)(As + arow * 72 + ac8) = ra;
        #pragma unroll
        for (int it = 0; it < 4; ++it)
            *(short8*)(Bs + (it * 32 + arow) * 72 + ac8) = rb[it];
    };

    f32x4 acc[2][2] = {};
    load_tile(0);
    for (int t = 0; t < 4; ++t) {
        __syncthreads();
        store_tile();
        __syncthreads();
        if (t < 3) load_tile(t + 1);
        #pragma unroll
        for (int ks = 0; ks < 2; ++ks) {
            short8 bf0 = *(const short8*)(Bs + (w * 32 + r15) * 72 + ks * 32 + g * 8);
            short8 bf1 = *(const short8*)(Bs + (w * 32 + 16 + r15) * 72 + ks * 32 + g * 8);
            #pragma unroll
            for (int m = 0; m < 2; ++m) {
                short8 af = *(const short8*)(As + (m * 16 + r15) * 72 + ks * 32 + g * 8);
                acc[m][0] = mfma16(af, bf0, acc[m][0]);
                acc[m][1] = mfma16(af, bf1, acc[m][1]);
            }
        }
    }
    __syncthreads();                              // all As/Bs reads done
    float* Ct = (float*)smem;                     // [128 co][30 px-pad]
    #pragma unroll
    for (int n = 0; n < 2; ++n)
        #pragma unroll
        for (int m = 0; m < 2; ++m)
            #pragma unroll
            for (int r = 0; r < 4; ++r) {
                int s = m * 16 + g * 4 + r;
                if (s < 28) Ct[(w * 32 + n * 16 + r15) * 30 + s] = acc[m][n][r];
            }
    __syncthreads();
    for (int idx = tid; idx < 128 * 28; idx += 256) {
        int col = idx / 28, s = idx - col * 28;
        ob[(size_t)(coQ + col) * 196 + px0 + s] = Ct[col * 30 + s] * kscale;
    }
}

// ---------------- GN pass 1: per-(group, quarter) partial sums ----------------
__global__ __launch_bounds__(256) void gn_stats(const float* __restrict__ out, char* wsb) {
    int q = blockIdx.x, bgid = blockIdx.y;
    const float4* base = (const float4*)(out + (size_t)bgid * 50176 + q * 12544);
    int tid = threadIdx.x;
    float s = 0.f, ss = 0.f;
    for (int i = tid; i < 3136; i += 256) {
        float4 v = base[i];
        s += v.x + v.y + v.z + v.w;
        ss += v.x * v.x + v.y * v.y + v.z * v.z + v.w * v.w;
    }
    __shared__ float rs[256], rss[256];
    rs[tid] = s; rss[tid] = ss;
    __syncthreads();
    for (int st = 128; st > 0; st >>= 1) {
        if (tid < st) { rs[tid] += rs[tid + st]; rss[tid] += rss[tid + st]; }
        __syncthreads();
    }
    if (tid == 0) {
        float* gns = (float*)(wsb + BO_GNS);
        gns[(bgid * 4 + q) * 2] = rs[0];
        gns[(bgid * 4 + q) * 2 + 1] = rss[0];
    }
}

// ---------------- GN pass 2: normalize + affine + residual + ReLU ----------------
__global__ __launch_bounds__(256) void gn_apply(
        float* __restrict__ out, const float* __restrict__ x,
        const float* __restrict__ gg, const float* __restrict__ gb, const char* wsb) {
    int bgid = blockIdx.x >> 4, six = blockIdx.x & 15;
    int g = bgid & 3;
    const float* gns = (const float*)(wsb + BO_GNS);
    float s = 0.f, q = 0.f;
    #pragma unroll
    for (int k = 0; k < 4; ++k) { s += gns[(bgid * 4 + k) * 2]; q += gns[(bgid * 4 + k) * 2 + 1]; }
    float mu = s * (1.f / 50176.f);
    float var = q * (1.f / 50176.f) - mu * mu;
    float rstd = rsqrtf(var + EPSN);

    size_t base = (size_t)bgid * 50176 + six * 3136;
    float4* po = (float4*)(out + base);
    const float4* px4 = (const float4*)(x + base);
    int tid = threadIdx.x;
    for (int i = tid; i < 784; i += 256) {
        int off = six * 3136 + i * 4;
        int gc = g * 256 + off / 196;
        float sc = gg[gc] * rstd;
        float sh = gb[gc] - mu * sc;
        float4 v = po[i], xv = px4[i];
        v.x = fmaxf(v.x * sc + sh + xv.x, 0.f);
        v.y = fmaxf(v.y * sc + sh + xv.y, 0.f);
        v.z = fmaxf(v.z * sc + sh + xv.z, 0.f);
        v.w = fmaxf(v.w * sc + sh + xv.w, 0.f);
        po[i] = v;
    }
}

// ---------------- launch ----------------
extern "C" void kernel_launch(void* const* d_in, const int* in_sizes, int n_in,
                              void* d_out, int out_size, void* d_ws, size_t ws_size,
                              hipStream_t stream) {
    (void)in_sizes; (void)n_in; (void)out_size; (void)ws_size;
    const float* x    = (const float*)d_in[0];
    const int*   mask = (const int*)d_in[1];
    const float* w1   = (const float*)d_in[2];
    const float* w2   = (const float*)d_in[3];
    const float* w3   = (const float*)d_in[4];
    const float* b1g  = (const float*)d_in[5];
    const float* b1b  = (const float*)d_in[6];
    const float* b1m  = (const float*)d_in[7];
    const float* b1v  = (const float*)d_in[8];
    const float* b2g  = (const float*)d_in[9];
    const float* b2b  = (const float*)d_in[10];
    const float* b2m  = (const float*)d_in[11];
    const float* b2v  = (const float*)d_in[12];
    const float* gng  = (const float*)d_in[13];
    const float* gnb  = (const float*)d_in[14];
    char* wsb = (char*)d_ws;
    float* out = (float*)d_out;

    maxabs_kernel<<<dim3(48, 3), 256, 0, stream>>>(w1, w2, w3, (float*)(wsb + BO_PMAX));
    prepw1_kernel<<<1024, 256, 0, stream>>>(w1, wsb);
    prepx_kernel<<<dim3(16, 32), 256, 0, stream>>>(x, mask, wsb);
    conv1_mfma<<<dim3(7, 4, 32), 256, 0, stream>>>(wsb, mask, b1g, b1b, b1m, b1v);
    prepw23_kernel<<<3328, 256, 0, stream>>>(w2, w3, wsb);      // overwrites dead xq
    conv2_mfma<<<dim3(7, 4, 32), 256, 0, stream>>>(wsb, mask, b2g, b2b, b2m, b2v);
    conv3_mfma<<<dim3(7, 8, 32), 256, 0, stream>>>(wsb, mask, out);
    gn_stats<<<dim3(4, 128), 256, 0, stream>>>(out, wsb);
    gn_apply<<<2048, 256, 0, stream>>>(out, x, gng, gnb, wsb);
}

// Round 8
// 101.622 us; speedup vs baseline: 6.8774x; 1.1489x over previous
//
#include <hip/hip_runtime.h>
#include <hip/hip_bf16.h>

typedef __attribute__((ext_vector_type(8))) short short8;
typedef __attribute__((ext_vector_type(4))) float f32x4;

#define PIX  196
#define EPSN 1e-5f

// ---------------- workspace byte layout (~20.85 MB, proven size range) ----------------
#define BO_XQ   256                      // [32][196][1024] bf16 = 12,845,056 B
#define BO_W2Q  BO_XQ                    // reuse after conv1: [3][9][256][256] bf16
#define BO_W3Q  (BO_XQ + 3538944)        // [3][1024][256] bf16
#define BO_H1Q  (BO_XQ + 12845056)       // [32][196][256] bf16
#define BO_H2Q  (BO_H1Q + 3211264)
#define BO_W1Q  (BO_H2Q + 3211264)       // [3][256][1024] bf16
#define BO_GNS  (BO_W1Q + 1572864)       // [32][4][2][4] float2 = 8 KB partial GN sums
#define BO_PMAX (BO_GNS + 8192)          // [3][48] f32

__device__ __forceinline__ float e_ascale(int e) { return e == 0 ? 3.f : (e == 1 ? 15.f : 255.f); }
__device__ __forceinline__ float e_nq(int e)     { return e == 0 ? 1.f : (e == 1 ? 7.f : 127.f); }

__device__ __forceinline__ f32x4 mfma16(short8 a, short8 b, f32x4 c) {
    return __builtin_amdgcn_mfma_f32_16x16x32_bf16(a, b, c, 0, 0, 0);
}
__device__ __forceinline__ float wmax_reduce(const char* wsb, int t) {
    const float* pm = (const float*)(wsb + BO_PMAX) + t * 48;
    float s = 0.f;
    #pragma unroll
    for (int k = 0; k < 48; ++k) s = fmaxf(s, pm[k]);
    return s + 1e-12f;
}

// ---------------- max|w| partials: [3][48] ----------------
__global__ __launch_bounds__(256) void maxabs_kernel(
        const float* __restrict__ w1, const float* __restrict__ w2,
        const float* __restrict__ w3, float* __restrict__ pmax) {
    int t = blockIdx.y;
    const float* w = t == 0 ? w1 : (t == 1 ? w2 : w3);
    int n = (t == 1) ? 256 * 256 * 9 : 256 * 1024;
    float m = 0.f;
    for (int i = blockIdx.x * 256 + threadIdx.x; i < n; i += 48 * 256)
        m = fmaxf(m, fabsf(w[i]));
    __shared__ float red[256];
    red[threadIdx.x] = m;
    __syncthreads();
    for (int s = 128; s > 0; s >>= 1) {
        if (threadIdx.x < s) red[threadIdx.x] = fmaxf(red[threadIdx.x], red[threadIdx.x + s]);
        __syncthreads();
    }
    if (threadIdx.x == 0) pmax[t * 48 + blockIdx.x] = red[0];
}

// ---------------- fused: w1 -> integer bf16 AND x -> qact NHWC bf16 ----------------
// grid 1536: [0,1024) = w1 quant; [1024,1536) = x prep (16 ci-chunks x 32 samples)
__global__ __launch_bounds__(256) void prep_w1x(
        const float* __restrict__ w1, const float* __restrict__ x,
        const int* __restrict__ mask, char* wsb) {
    __shared__ float xs[64][197];
    if (blockIdx.x < 1024) {
        int idx = blockIdx.x * 256 + threadIdx.x;           // 262144 exactly
        float s = wmax_reduce(wsb, 0);
        float v = w1[idx];
        __hip_bfloat16* dst = (__hip_bfloat16*)(wsb + BO_W1Q);
        #pragma unroll
        for (int e = 0; e < 3; ++e)
            dst[e * 262144 + idx] = __float2bfloat16(rintf(v / s * e_nq(e)));
    } else {
        int bx = blockIdx.x - 1024;
        int b = bx >> 4, c0 = (bx & 15) * 64;
        float ascale = e_ascale(mask[b]);
        int tid = threadIdx.x;
        for (int idx = tid; idx < 64 * 196; idx += 256) {
            int ci = idx / 196, p = idx - ci * 196;
            xs[ci][p] = x[((size_t)b * 1024 + c0 + ci) * 196 + p];
        }
        __syncthreads();
        __hip_bfloat16* xq = (__hip_bfloat16*)(wsb + BO_XQ);
        for (int idx = tid; idx < 196 * 64; idx += 256) {
            int p = idx / 64, ci = idx - p * 64;
            float v = fminf(fmaxf(xs[ci][p], 0.f), 1.f);
            xq[((size_t)b * 196 + p) * 1024 + c0 + ci] = __float2bfloat16(rintf(v * ascale));
        }
    }
}

// ---------------- w2,w3 -> integer bf16 (after conv1; overwrites dead xq) ----------------
__global__ __launch_bounds__(256) void prepw23_kernel(
        const float* __restrict__ w2, const float* __restrict__ w3, char* wsb) {
    int idx = blockIdx.x * 256 + threadIdx.x;           // 851968 = 589824 + 262144
    if (idx < 589824) {
        float s = wmax_reduce(wsb, 1);
        float v = w2[idx];
        int co = idx / 2304, r = idx - co * 2304, ci = r / 9, tap = r - ci * 9;
        __hip_bfloat16* dst = (__hip_bfloat16*)(wsb + BO_W2Q);
        size_t off = ((size_t)tap * 256 + co) * 256 + ci;
        #pragma unroll
        for (int e = 0; e < 3; ++e)
            dst[e * 589824 + off] = __float2bfloat16(rintf(v / s * e_nq(e)));
    } else {
        int i2 = idx - 589824;
        float s = wmax_reduce(wsb, 2);
        float v = w3[i2];
        __hip_bfloat16* dst = (__hip_bfloat16*)(wsb + BO_W3Q);
        #pragma unroll
        for (int e = 0; e < 3; ++e)
            dst[e * 262144 + i2] = __float2bfloat16(rintf(v / s * e_nq(e)));
    }
}

// ================= conv1: 1x1 1024->256 + BN1 + ReLU + qact =================
// grid (4 M(56px), 2 N(128co), 32). 4 waves; wave = 4 M-frags x 2 N-frags(32co). BK=128.
__global__ __launch_bounds__(256) void conv1_mfma(
        char* wsb, const int* __restrict__ mask,
        const float* __restrict__ bg, const float* __restrict__ bb,
        const float* __restrict__ bm, const float* __restrict__ bv) {
    int b = blockIdx.z;
    int e = mask[b];
    float ascale = e_ascale(e);
    float s1 = wmax_reduce(wsb, 0);
    float kscale = (s1 / e_nq(e)) / ascale;

    const short* xq  = (const short*)(wsb + BO_XQ) + (size_t)b * 196 * 1024;
    const short* w1q = (const short*)(wsb + BO_W1Q) + (size_t)e * 256 * 1024;
    __hip_bfloat16* h1q = (__hip_bfloat16*)(wsb + BO_H1Q) + (size_t)b * 196 * 256;

    __shared__ short As[64 * 136];    // 17.4 KB (rows 56..63 = clamped dup, outputs masked)
    __shared__ short Bs[128 * 136];   // 34.8 KB

    int tid = threadIdx.x, w = tid >> 6, lane = tid & 63, r15 = lane & 15, g = lane >> 4;
    int px0 = blockIdx.x * 56, coB = blockIdx.y * 128;

    short8 ra[4], rb[8];
    auto load_tile = [&](int t) {
        int k0 = t * 128;
        #pragma unroll
        for (int ii = 0; ii < 4; ++ii) {
            int idx = ii * 256 + tid;
            int arow = idx >> 4, ac = (idx & 15) * 8;
            ra[ii] = *(const short8*)(xq + (size_t)min(px0 + arow, 195) * 1024 + k0 + ac);
        }
        #pragma unroll
        for (int ii = 0; ii < 8; ++ii) {
            int idx = ii * 256 + tid;
            int brow = idx >> 4, bc = (idx & 15) * 8;
            rb[ii] = *(const short8*)(w1q + (size_t)(coB + brow) * 1024 + k0 + bc);
        }
    };
    auto store_tile = [&]() {
        #pragma unroll
        for (int ii = 0; ii < 4; ++ii) {
            int idx = ii * 256 + tid;
            *(short8*)(As + (idx >> 4) * 136 + (idx & 15) * 8) = ra[ii];
        }
        #pragma unroll
        for (int ii = 0; ii < 8; ++ii) {
            int idx = ii * 256 + tid;
            *(short8*)(Bs + (idx >> 4) * 136 + (idx & 15) * 8) = rb[ii];
        }
    };

    f32x4 acc[4][2] = {};
    load_tile(0);
    for (int t = 0; t < 8; ++t) {
        __syncthreads();
        store_tile();
        __syncthreads();
        if (t < 7) load_tile(t + 1);
        #pragma unroll
        for (int ks = 0; ks < 4; ++ks) {
            short8 bf0 = *(const short8*)(Bs + (w * 32 + r15) * 136 + ks * 32 + g * 8);
            short8 bf1 = *(const short8*)(Bs + (w * 32 + 16 + r15) * 136 + ks * 32 + g * 8);
            #pragma unroll
            for (int m = 0; m < 4; ++m) {
                short8 af = *(const short8*)(As + (m * 16 + r15) * 136 + ks * 32 + g * 8);
                acc[m][0] = mfma16(af, bf0, acc[m][0]);
                acc[m][1] = mfma16(af, bf1, acc[m][1]);
            }
        }
    }
    #pragma unroll
    for (int n = 0; n < 2; ++n) {
        int co = coB + w * 32 + n * 16 + r15;
        float inv = bg[co] * rsqrtf(bv[co] + EPSN);
        float mm = kscale * inv;
        float beta = bb[co] - bm[co] * inv;
        #pragma unroll
        for (int m = 0; m < 4; ++m)
            #pragma unroll
            for (int r = 0; r < 4; ++r) {
                int s = m * 16 + g * 4 + r, px = px0 + s;
                if (s < 56 && px < 196) {
                    float h = fmaxf(acc[m][n][r] * mm + beta, 0.f);
                    h1q[(size_t)px * 256 + co] = __float2bfloat16(rintf(fminf(h, 1.f) * ascale));
                }
            }
    }
}

// ================= conv2: 3x3 256->256 + BN2 + ReLU + qact =================
// grid (4 M(4 rows = 56px), 4 N(64co), 32). 4 waves; wave = 4 M-frags x 16co.
__global__ __launch_bounds__(256) void conv2_mfma(
        char* wsb, const int* __restrict__ mask,
        const float* __restrict__ bg, const float* __restrict__ bb,
        const float* __restrict__ bm, const float* __restrict__ bv) {
    int b = blockIdx.z;
    int e = mask[b];
    float ascale = e_ascale(e);
    float s2 = wmax_reduce(wsb, 1);
    float kscale = (s2 / e_nq(e)) / ascale;

    const short* h1q = (const short*)(wsb + BO_H1Q) + (size_t)b * 196 * 256;
    const short* w2q = (const short*)(wsb + BO_W2Q) + (size_t)e * 589824;
    __hip_bfloat16* h2q = (__hip_bfloat16*)(wsb + BO_H2Q) + (size_t)b * 196 * 256;

    __shared__ short Xs[6 * 16 * 40];    // rows r0-1..r0+4, cols -1..14, 32ci (stride 40)
    __shared__ short Ws9[9 * 64 * 40];   // [tap][co][32ci]

    int tid = threadIdx.x, w = tid >> 6, lane = tid & 63, r15 = lane & 15, g = lane >> 4;
    int r0 = blockIdx.x * 4;
    int px0 = blockIdx.x * 56;
    int coB = blockIdx.y * 64;
    const short8 z8 = {0, 0, 0, 0, 0, 0, 0, 0};

    int wco = tid >> 2, wc8 = (tid & 3) * 8;

    int rr[4], cc[4];
    #pragma unroll
    for (int m = 0; m < 4; ++m) {
        int s0 = min(m * 16 + r15, 55);
        rr[m] = s0 / 14; cc[m] = s0 - rr[m] * 14;
    }

    short8 rx[2], rw[9];
    auto load_tile = [&](int sl) {
        int ci0 = sl * 32;
        #pragma unroll
        for (int ii = 0; ii < 2; ++ii) {
            int idx = ii * 256 + tid;
            rx[ii] = z8;
            if (idx < 384) {
                int xc = idx & 3, xsx = (idx >> 2) & 15, xsy = idx >> 6;
                int iy = r0 - 1 + xsy, ix = xsx - 1;
                if ((unsigned)iy < 14u && (unsigned)ix < 14u)
                    rx[ii] = *(const short8*)(h1q + (size_t)(iy * 14 + ix) * 256 + ci0 + xc * 8);
            }
        }
        #pragma unroll
        for (int tap = 0; tap < 9; ++tap)
            rw[tap] = *(const short8*)(w2q + ((size_t)tap * 256 + coB + wco) * 256 + ci0 + wc8);
    };
    auto store_tile = [&]() {
        #pragma unroll
        for (int ii = 0; ii < 2; ++ii) {
            int idx = ii * 256 + tid;
            if (idx < 384) {
                int xc = idx & 3, xsx = (idx >> 2) & 15, xsy = idx >> 6;
                *(short8*)(Xs + (xsy * 16 + xsx) * 40 + xc * 8) = rx[ii];
            }
        }
        #pragma unroll
        for (int tap = 0; tap < 9; ++tap)
            *(short8*)(Ws9 + (tap * 64 + wco) * 40 + wc8) = rw[tap];
    };

    f32x4 acc[4] = {};
    load_tile(0);
    for (int sl = 0; sl < 8; ++sl) {
        __syncthreads();
        store_tile();
        __syncthreads();
        if (sl < 7) load_tile(sl + 1);
        #pragma unroll
        for (int tap = 0; tap < 9; ++tap) {
            int ty = tap / 3, tx = tap - ty * 3;
            short8 bf = *(const short8*)(Ws9 + (tap * 64 + w * 16 + r15) * 40 + g * 8);
            #pragma unroll
            for (int m = 0; m < 4; ++m) {
                short8 af = *(const short8*)(Xs + ((rr[m] + ty) * 16 + cc[m] + tx) * 40 + g * 8);
                acc[m] = mfma16(af, bf, acc[m]);
            }
        }
    }
    int co = coB + w * 16 + r15;
    float inv = bg[co] * rsqrtf(bv[co] + EPSN);
    float mm = kscale * inv;
    float beta = bb[co] - bm[co] * inv;
    #pragma unroll
    for (int m = 0; m < 4; ++m)
        #pragma unroll
        for (int r = 0; r < 4; ++r) {
            int s = m * 16 + g * 4 + r, px = px0 + s;
            if (s < 56 && px < 196) {
                float h = fmaxf(acc[m][r] * mm + beta, 0.f);
                h2q[(size_t)px * 256 + co] = __float2bfloat16(rintf(fminf(h, 1.f) * ascale));
            }
        }
}

// ================= conv3: 1x1 256->1024 + fused GN partial stats =================
// grid (4 M(56px), 8 N(128co), 32). 4 waves; wave = 4 M x 2 N frags. BK=64.
__global__ __launch_bounds__(256) void conv3_mfma(
        char* wsb, const int* __restrict__ mask, float* __restrict__ out) {
    int b = blockIdx.z;
    int e = mask[b];
    float ascale = e_ascale(e);
    float s3 = wmax_reduce(wsb, 2);
    float kscale = (s3 / e_nq(e)) / ascale;

    const short* h2q = (const short*)(wsb + BO_H2Q) + (size_t)b * 196 * 256;
    const short* w3q = (const short*)(wsb + BO_W3Q) + (size_t)e * 1024 * 256;
    float* ob = out + (size_t)b * 1024 * 196;

    __shared__ float Ct[128 * 58];       // 29,696 B; aliased by As|Bs (27,648 B)
    __shared__ float rs[256], rss[256];
    short* As = (short*)Ct;              // 64*72 shorts
    short* Bs = As + 64 * 72;            // 128*72 shorts

    int tid = threadIdx.x, w = tid >> 6, lane = tid & 63, r15 = lane & 15, g = lane >> 4;
    int px0 = blockIdx.x * 56;
    int coQ = blockIdx.y * 128;
    int gslot = (b * 4 + (blockIdx.y >> 1)) * 8 + (blockIdx.y & 1) * 4 + blockIdx.x;

    short8 ra[2], rb[4];
    auto load_tile = [&](int t) {
        int k0 = t * 64;
        #pragma unroll
        for (int ii = 0; ii < 2; ++ii) {
            int idx = ii * 256 + tid;
            int arow = idx >> 3, ac = (idx & 7) * 8;
            ra[ii] = *(const short8*)(h2q + (size_t)min(px0 + arow, 195) * 256 + k0 + ac);
        }
        #pragma unroll
        for (int ii = 0; ii < 4; ++ii) {
            int idx = ii * 256 + tid;
            int brow = idx >> 3, bc = (idx & 7) * 8;
            rb[ii] = *(const short8*)(w3q + (size_t)(coQ + brow) * 256 + k0 + bc);
        }
    };
    auto store_tile = [&]() {
        #pragma unroll
        for (int ii = 0; ii < 2; ++ii) {
            int idx = ii * 256 + tid;
            *(short8*)(As + (idx >> 3) * 72 + (idx & 7) * 8) = ra[ii];
        }
        #pragma unroll
        for (int ii = 0; ii < 4; ++ii) {
            int idx = ii * 256 + tid;
            *(short8*)(Bs + (idx >> 3) * 72 + (idx & 7) * 8) = rb[ii];
        }
    };

    f32x4 acc[4][2] = {};
    load_tile(0);
    for (int t = 0; t < 4; ++t) {
        __syncthreads();
        store_tile();
        __syncthreads();
        if (t < 3) load_tile(t + 1);
        #pragma unroll
        for (int ks = 0; ks < 2; ++ks) {
            short8 bf0 = *(const short8*)(Bs + (w * 32 + r15) * 72 + ks * 32 + g * 8);
            short8 bf1 = *(const short8*)(Bs + (w * 32 + 16 + r15) * 72 + ks * 32 + g * 8);
            #pragma unroll
            for (int m = 0; m < 4; ++m) {
                short8 af = *(const short8*)(As + (m * 16 + r15) * 72 + ks * 32 + g * 8);
                acc[m][0] = mfma16(af, bf0, acc[m][0]);
                acc[m][1] = mfma16(af, bf1, acc[m][1]);
            }
        }
    }
    __syncthreads();                     // all As/Bs reads complete before Ct overwrite
    #pragma unroll
    for (int n = 0; n < 2; ++n)
        #pragma unroll
        for (int m = 0; m < 4; ++m)
            #pragma unroll
            for (int r = 0; r < 4; ++r) {
                int s = m * 16 + g * 4 + r;
                if (s < 56) Ct[(w * 32 + n * 16 + r15) * 58 + s] = acc[m][n][r];
            }
    __syncthreads();
    float sum = 0.f, ss = 0.f;
    for (int idx = tid; idx < 128 * 56; idx += 256) {
        int col = idx / 56, s = idx - col * 56, px = px0 + s;
        if (px < 196) {
            float v = Ct[col * 58 + s] * kscale;
            ob[(size_t)(coQ + col) * 196 + px] = v;
            sum += v; ss += v * v;
        }
    }
    rs[tid] = sum; rss[tid] = ss;
    __syncthreads();
    for (int st = 128; st > 0; st >>= 1) {
        if (tid < st) { rs[tid] += rs[tid + st]; rss[tid] += rss[tid + st]; }
        __syncthreads();
    }
    if (tid == 0) {
        float* gns = (float*)(wsb + BO_GNS);
        gns[gslot * 2] = rs[0];
        gns[gslot * 2 + 1] = rss[0];
    }
}

// ---------------- GN pass 2: normalize + affine + residual + ReLU ----------------
__global__ __launch_bounds__(256) void gn_apply(
        float* __restrict__ out, const float* __restrict__ x,
        const float* __restrict__ gg, const float* __restrict__ gb, const char* wsb) {
    int bgid = blockIdx.x >> 4, six = blockIdx.x & 15;
    int g = bgid & 3;
    const float* gns = (const float*)(wsb + BO_GNS);
    float s = 0.f, q = 0.f;
    #pragma unroll
    for (int k = 0; k < 8; ++k) { s += gns[(bgid * 8 + k) * 2]; q += gns[(bgid * 8 + k) * 2 + 1]; }
    float mu = s * (1.f / 50176.f);
    float var = q * (1.f / 50176.f) - mu * mu;
    float rstd = rsqrtf(var + EPSN);

    size_t base = (size_t)bgid * 50176 + six * 3136;
    float4* po = (float4*)(out + base);
    const float4* px4 = (const float4*)(x + base);
    int tid = threadIdx.x;
    for (int i = tid; i < 784; i += 256) {
        int off = six * 3136 + i * 4;
        int gc = g * 256 + off / 196;
        float sc = gg[gc] * rstd;
        float sh = gb[gc] - mu * sc;
        float4 v = po[i], xv = px4[i];
        v.x = fmaxf(v.x * sc + sh + xv.x, 0.f);
        v.y = fmaxf(v.y * sc + sh + xv.y, 0.f);
        v.z = fmaxf(v.z * sc + sh + xv.z, 0.f);
        v.w = fmaxf(v.w * sc + sh + xv.w, 0.f);
        po[i] = v;
    }
}

// ---------------- launch ----------------
extern "C" void kernel_launch(void* const* d_in, const int* in_sizes, int n_in,
                              void* d_out, int out_size, void* d_ws, size_t ws_size,
                              hipStream_t stream) {
    (void)in_sizes; (void)n_in; (void)out_size; (void)ws_size;
    const float* x    = (const float*)d_in[0];
    const int*   mask = (const int*)d_in[1];
    const float* w1   = (const float*)d_in[2];
    const float* w2   = (const float*)d_in[3];
    const float* w3   = (const float*)d_in[4];
    const float* b1g  = (const float*)d_in[5];
    const float* b1b  = (const float*)d_in[6];
    const float* b1m  = (const float*)d_in[7];
    const float* b1v  = (const float*)d_in[8];
    const float* b2g  = (const float*)d_in[9];
    const float* b2b  = (const float*)d_in[10];
    const float* b2m  = (const float*)d_in[11];
    const float* b2v  = (const float*)d_in[12];
    const float* gng  = (const float*)d_in[13];
    const float* gnb  = (const float*)d_in[14];
    char* wsb = (char*)d_ws;
    float* out = (float*)d_out;

    maxabs_kernel<<<dim3(48, 3), 256, 0, stream>>>(w1, w2, w3, (float*)(wsb + BO_PMAX));
    prep_w1x<<<1536, 256, 0, stream>>>(w1, x, mask, wsb);
    conv1_mfma<<<dim3(4, 2, 32), 256, 0, stream>>>(wsb, mask, b1g, b1b, b1m, b1v);
    prepw23_kernel<<<3328, 256, 0, stream>>>(w2, w3, wsb);      // overwrites dead xq
    conv2_mfma<<<dim3(4, 4, 32), 256, 0, stream>>>(wsb, mask, b2g, b2b, b2m, b2v);
    conv3_mfma<<<dim3(4, 8, 32), 256, 0, stream>>>(wsb, mask, out);
    gn_apply<<<2048, 256, 0, stream>>>(out, x, gng, gnb, wsb);
}